// Round 1
// baseline (327.423 us; speedup 1.0000x reference)
//
#include <hip/hip_runtime.h>

namespace {

constexpr int NQ = 12;
constexpr int NL = 3;
constexpr int FEAT = 64;
constexpr float PI_F = 3.14159265358979323846f;

// ---- compile-time tracking of the deferred CNOT permutation (GF(2) linear map) ----
// Storage invariant: st_phys[p] = amp[i] with p = P(i).
// Single-qubit gate on logical bit b pairs p and p ^ col_b(P); the element with
// logical bit==0 is the one with parity(row_b(P^{-1}) & p) == 0.
// CNOT(c,t) updates: col[bc] ^= col[bt];  rowinv[bt] ^= rowinv[bc].
struct Maps {
  unsigned m[NL][NQ];   // pairing mask per (layer, qubit)
  unsigned rv[NL][NQ];  // parity row per (layer, qubit)
  unsigned rf[NQ];      // final parity rows for <Z_q>
  bool ok;
};

constexpr Maps compute_maps() {
  Maps mp{};
  unsigned col[NQ] = {}, row[NQ] = {};
  for (int b = 0; b < NQ; ++b) { col[b] = 1u << b; row[b] = 1u << b; }
  mp.ok = true;
  for (int L = 0; L < NL; ++L) {
    for (int q = 0; q < NQ; ++q) {
      mp.m[L][q]  = col[NQ - 1 - q];
      mp.rv[L][q] = row[NQ - 1 - q];
      unsigned x = mp.m[L][q] & mp.rv[L][q];
      int pc = 0;
      for (int i = 0; i < NQ; ++i) pc ^= (int)((x >> i) & 1u);
      if (pc != 1) mp.ok = false;  // pair must straddle logical 0/1
    }
    for (int q = 0; q < NQ; ++q) {
      int bc = NQ - 1 - q;
      int bt = NQ - 1 - ((q + 1) % NQ);
      col[bc] ^= col[bt];
      row[bt] ^= row[bc];
    }
  }
  for (int q = 0; q < NQ; ++q) mp.rf[q] = row[NQ - 1 - q];
  return mp;
}

constexpr Maps MP = compute_maps();
static_assert(MP.ok, "pairing invariant violated");

__device__ __forceinline__ float shflx(float v, int m) {
  return __shfl_xor(v, m, 64);
}

// out = A*a + B*p (complex), with A=(ar, aiU), B=(brU, b0i)
__device__ __forceinline__ float2 upd(float2 a, float2 p, float ar, float aiU, float brU, float b0i) {
  float2 o;
  o.x = ar * a.x - aiU * a.y + brU * p.x - b0i * p.y;
  o.y = ar * a.y + aiU * a.x + brU * p.y + b0i * p.x;
  return o;
}

// Fused U = RZ(2*phihalf) * RY(2*ghalf):
// v0' = e^{-i phi}(c v0 - s v1); v1' = e^{+i phi}(s v0 + c v1)
// Per-amp: out = A_t*a + B_t*partner, A_t=(ar, +-ai), B_t=(-+b0r... signs via parity t.
template<unsigned M, unsigned R>
__device__ __forceinline__ void gate(float2* st, float ghalf, float phihalf, int lane) {
  float s, c, sf, cf;
  __sincosf(ghalf, &s, &c);
  __sincosf(phihalf, &sf, &cf);
  float ar  = c * cf;
  float ai  = -c * sf;
  float b0r = -s * cf;
  float b0i = s * sf;
  constexpr unsigned MHI = (M >> 6) & 63u;
  constexpr unsigned MLO = M & 63u;
  constexpr unsigned RHI = (R >> 6) & 63u;
  constexpr unsigned RLO = R & 63u;
  float sL = (__popc((int)(RLO & (unsigned)lane)) & 1) ? -1.f : 1.f;
  float aiS = sL * ai;
  float brS = sL * b0r;
  if constexpr (MLO == 0u) {
    // register-local pairing
    constexpr unsigned TB = MHI & (~MHI + 1u);
    #pragma unroll
    for (int r = 0; r < 64; ++r) {
      if ((r & (int)TB) == 0) {
        int r2 = r ^ (int)MHI;
        bool rp = (__builtin_popcount((unsigned)r & RHI) & 1) != 0;
        float aiU = rp ? -aiS : aiS;
        float brU = rp ? -brS : brS;
        float2 a = st[r], b = st[r2];
        st[r]  = upd(a, b, ar, aiU, brU, b0i);
        st[r2] = upd(b, a, ar, -aiU, -brU, b0i);  // partner parity is opposite (R.M==1, MLO==0)
      }
    }
  } else if constexpr (MHI == 0u) {
    // pure cross-lane pairing
    #pragma unroll
    for (int r = 0; r < 64; ++r) {
      float2 p;
      p.x = shflx(st[r].x, (int)MLO);
      p.y = shflx(st[r].y, (int)MLO);
      bool rp = (__builtin_popcount((unsigned)r & RHI) & 1) != 0;
      float aiU = rp ? -aiS : aiS;
      float brU = rp ? -brS : brS;
      st[r] = upd(st[r], p, ar, aiU, brU, b0i);
    }
  } else {
    // mixed: partner = other lane AND other register
    constexpr unsigned TB = MHI & (~MHI + 1u);
    #pragma unroll
    for (int r = 0; r < 64; ++r) {
      if ((r & (int)TB) == 0) {
        int r2 = r ^ (int)MHI;
        float2 pa, pb;
        pa.x = shflx(st[r2].x, (int)MLO);
        pa.y = shflx(st[r2].y, (int)MLO);
        pb.x = shflx(st[r].x, (int)MLO);
        pb.y = shflx(st[r].y, (int)MLO);
        bool rp  = (__builtin_popcount((unsigned)r  & RHI) & 1) != 0;
        bool rp2 = (__builtin_popcount((unsigned)r2 & RHI) & 1) != 0;
        float aiU  = rp  ? -aiS : aiS;
        float brU  = rp  ? -brS : brS;
        float aiU2 = rp2 ? -aiS : aiS;
        float brU2 = rp2 ? -brS : brS;
        float2 a = st[r], b = st[r2];
        st[r]  = upd(a, pa, ar, aiU,  brU,  b0i);
        st[r2] = upd(b, pb, ar, aiU2, brU2, b0i);
      }
    }
  }
}

template<int L, int Q>
__device__ __forceinline__ void do_gates(float2* st, const float* ang, const float* __restrict__ qp, int lane) {
  if constexpr (Q == NQ) {
    if constexpr (L + 1 < NL) do_gates<L + 1, 0>(st, ang, qp, lane);
  } else {
    float th0 = qp[(L * NQ + Q) * 2 + 0];
    float th1 = qp[(L * NQ + Q) * 2 + 1];
    gate<MP.m[L][Q], MP.rv[L][Q]>(st, 0.5f * (ang[Q] + th0), 0.5f * th1, lane);
    do_gates<L, Q + 1>(st, ang, qp, lane);
  }
}

template<int Q>
__device__ __forceinline__ void measure(const float* pr, float& outv, int lane) {
  if constexpr (Q < NQ) {
    constexpr unsigned RF  = MP.rf[Q];
    constexpr unsigned RHI = (RF >> 6) & 63u;
    constexpr unsigned RLO = RF & 63u;
    float acc = 0.f;
    #pragma unroll
    for (int r = 0; r < 64; ++r) {
      bool rp = (__builtin_popcount((unsigned)r & RHI) & 1) != 0;
      acc += rp ? -pr[r] : pr[r];
    }
    float sLn = (__popc((int)(RLO & (unsigned)lane)) & 1) ? -1.f : 1.f;
    acc *= sLn;
    #pragma unroll
    for (int k = 1; k < 64; k <<= 1) acc += shflx(acc, k);
    if (lane == Q) outv = acc;
    measure<Q + 1>(pr, outv, lane);
  }
}

__global__ __launch_bounds__(64) void qtr_kernel(const float* __restrict__ x,
                                                 const float* __restrict__ W,
                                                 const float* __restrict__ qp,
                                                 float* __restrict__ out) {
  int b = blockIdx.x;
  int lane = threadIdx.x;

  // angles[q] = pi * tanh(dot(x[b], W[q])) — lane-parallel dot + butterfly reduce
  float xv = x[b * FEAT + lane];
  float ang[NQ];
  #pragma unroll
  for (int q = 0; q < NQ; ++q) {
    float prod = xv * W[q * FEAT + lane];
    #pragma unroll
    for (int k = 1; k < 64; k <<= 1) prod += shflx(prod, k);
    ang[q] = PI_F * tanhf(prod);
  }

  // |0...0>
  float2 st[64];
  #pragma unroll
  for (int r = 0; r < 64; ++r) st[r] = make_float2(0.f, 0.f);
  if (lane == 0) st[0].x = 1.f;

  do_gates<0, 0>(st, ang, qp, lane);

  // probabilities and parity-signed sums for <Z_q>
  float pr[64];
  #pragma unroll
  for (int r = 0; r < 64; ++r) pr[r] = st[r].x * st[r].x + st[r].y * st[r].y;

  float outv = 0.f;
  measure<0>(pr, outv, lane);

  if (lane < NQ) out[b * NQ + lane] = outv;
}

}  // namespace

extern "C" void kernel_launch(void* const* d_in, const int* in_sizes, int n_in,
                              void* d_out, int out_size, void* d_ws, size_t ws_size,
                              hipStream_t stream) {
  const float* x  = (const float*)d_in[0];
  const float* W  = (const float*)d_in[1];
  const float* qp = (const float*)d_in[2];
  float* out = (float*)d_out;
  qtr_kernel<<<8192, 64, 0, stream>>>(x, W, qp, out);
}

// Round 2
// 240.585 us; speedup vs baseline: 1.3609x; 1.3609x over previous
//
#include <hip/hip_runtime.h>

namespace {

constexpr int NQ = 12;
constexpr int NL = 3;
constexpr int FEAT = 64;
constexpr float PI_F = 3.14159265358979323846f;

// ---- compile-time tracking of the deferred CNOT permutation (GF(2) linear map) ----
// Storage invariant: st_phys[p] = amp[i] with p = P(i).
// Single-qubit gate on logical bit b pairs p and p ^ col_b(P); the element with
// logical bit==0 is the one with parity(row_b(P^{-1}) & p) == 0.
// CNOT(c,t) updates: col[bc] ^= col[bt];  rowinv[bt] ^= rowinv[bc].
struct Maps {
  unsigned m[NL][NQ];   // pairing mask per (layer, qubit)
  unsigned rv[NL][NQ];  // parity row per (layer, qubit)
  unsigned rf[NQ];      // final parity rows for <Z_q>
  bool ok;
};

constexpr Maps compute_maps() {
  Maps mp{};
  unsigned col[NQ] = {}, row[NQ] = {};
  for (int b = 0; b < NQ; ++b) { col[b] = 1u << b; row[b] = 1u << b; }
  mp.ok = true;
  for (int L = 0; L < NL; ++L) {
    for (int q = 0; q < NQ; ++q) {
      mp.m[L][q]  = col[NQ - 1 - q];
      mp.rv[L][q] = row[NQ - 1 - q];
      unsigned x = mp.m[L][q] & mp.rv[L][q];
      int pc = 0;
      for (int i = 0; i < NQ; ++i) pc ^= (int)((x >> i) & 1u);
      if (pc != 1) mp.ok = false;  // pair must straddle logical 0/1
    }
    for (int q = 0; q < NQ; ++q) {
      int bc = NQ - 1 - q;
      int bt = NQ - 1 - ((q + 1) % NQ);
      col[bc] ^= col[bt];
      row[bt] ^= row[bc];
    }
  }
  for (int q = 0; q < NQ; ++q) mp.rf[q] = row[NQ - 1 - q];
  return mp;
}

constexpr Maps MP = compute_maps();
static_assert(MP.ok, "pairing invariant violated");

constexpr bool par6(unsigned x) {
  return ((__builtin_popcount(x & 63u)) & 1) != 0;
}

// xor-shuffle across lanes with compile-time mask.
// mask<32 -> one ds_swizzle (xor mode, imm offset, no address VALU).
// bit5 set -> shfl_xor(32) for the half-swap, then swizzle the rest.
template<unsigned MLO>
__device__ __forceinline__ float shx(float v) {
  if constexpr (MLO == 0u) {
    return v;
  } else if constexpr ((MLO & 32u) == 0u) {
    constexpr int off = (int)((MLO << 10) | 0x1fu);
    return __int_as_float(__builtin_amdgcn_ds_swizzle(__float_as_int(v), off));
  } else {
    float t = __shfl_xor(v, 32, 64);
    constexpr unsigned rest = MLO & 31u;
    if constexpr (rest != 0u) {
      constexpr int off = (int)((rest << 10) | 0x1fu);
      t = __int_as_float(__builtin_amdgcn_ds_swizzle(__float_as_int(t), off));
    }
    return t;
  }
}

// out = A*a + B*p (complex), with A=(ar, aiU), B=(brU, b0i)
__device__ __forceinline__ float2 upd(float2 a, float2 p, float ar, float aiU, float brU, float b0i) {
  float2 o;
  o.x = ar * a.x - aiU * a.y + brU * p.x - b0i * p.y;
  o.y = ar * a.y + aiU * a.x + brU * p.y + b0i * p.x;
  return o;
}

// Fused U = RZ(2*phihalf) * RY(2*ghalf)
template<unsigned M, unsigned R>
__device__ __forceinline__ void gate(float2* st, float ghalf, float phihalf, int lane) {
  float s, c, sf, cf;
  __sincosf(ghalf, &s, &c);
  __sincosf(phihalf, &sf, &cf);
  float ar  = c * cf;
  float ai  = -c * sf;
  float b0r = -s * cf;
  float b0i = s * sf;
  constexpr unsigned MHI = (M >> 6) & 63u;
  constexpr unsigned MLO = M & 63u;
  constexpr unsigned RHI = (R >> 6) & 63u;
  constexpr unsigned RLO = R & 63u;
  float sL = (__popc((int)(RLO & (unsigned)lane)) & 1) ? -1.f : 1.f;
  float aiS = sL * ai;
  float brS = sL * b0r;
  if constexpr (MLO == 0u) {
    // register-local pairing
    constexpr unsigned TB = MHI & (~MHI + 1u);
    #pragma unroll
    for (int r = 0; r < 64; ++r) {
      if ((r & (int)TB) == 0) {
        int r2 = r ^ (int)MHI;
        constexpr unsigned RHIc = RHI;  // keep constexpr in scope
        float aiU = par6((unsigned)0) ? 0.f : 0.f;  // placeholder, real below
        (void)aiU;
        bool rp = (__builtin_popcount((unsigned)r & RHIc) & 1) != 0;
        float aiU1 = rp ? -aiS : aiS;
        float brU1 = rp ? -brS : brS;
        float2 a = st[r], b = st[r2];
        st[r]  = upd(a, b, ar, aiU1, brU1, b0i);
        st[r2] = upd(b, a, ar, -aiU1, -brU1, b0i);  // partner parity opposite (parity(M&R)==1, MLO==0)
      }
    }
  } else if constexpr (MHI == 0u) {
    // pure cross-lane pairing
    #pragma unroll
    for (int r = 0; r < 64; ++r) {
      float2 p;
      p.x = shx<MLO>(st[r].x);
      p.y = shx<MLO>(st[r].y);
      bool rp = (__builtin_popcount((unsigned)r & RHI) & 1) != 0;
      float aiU = rp ? -aiS : aiS;
      float brU = rp ? -brS : brS;
      st[r] = upd(st[r], p, ar, aiU, brU, b0i);
    }
  } else {
    // mixed: partner = other lane AND other register
    constexpr unsigned TB = MHI & (~MHI + 1u);
    #pragma unroll
    for (int r = 0; r < 64; ++r) {
      if ((r & (int)TB) == 0) {
        int r2 = r ^ (int)MHI;
        float2 pa, pb;
        pa.x = shx<MLO>(st[r2].x);
        pa.y = shx<MLO>(st[r2].y);
        pb.x = shx<MLO>(st[r].x);
        pb.y = shx<MLO>(st[r].y);
        bool rp  = (__builtin_popcount((unsigned)r  & RHI) & 1) != 0;
        bool rp2 = (__builtin_popcount((unsigned)r2 & RHI) & 1) != 0;
        float aiU  = rp  ? -aiS : aiS;
        float brU  = rp  ? -brS : brS;
        float aiU2 = rp2 ? -aiS : aiS;
        float brU2 = rp2 ? -brS : brS;
        float2 a = st[r], b = st[r2];
        st[r]  = upd(a, pa, ar, aiU,  brU,  b0i);
        st[r2] = upd(b, pb, ar, aiU2, brU2, b0i);
      }
    }
  }
}

template<int L, int Q>
__device__ __forceinline__ void do_gates(float2* st, const float* ang, const float* __restrict__ qp, int lane) {
  if constexpr (Q == NQ) {
    if constexpr (L + 1 < NL) do_gates<L + 1, 0>(st, ang, qp, lane);
  } else {
    float th0 = qp[(L * NQ + Q) * 2 + 0];
    float th1 = qp[(L * NQ + Q) * 2 + 1];
    gate<MP.m[L][Q], MP.rv[L][Q]>(st, 0.5f * (ang[Q] + th0), 0.5f * th1, lane);
    do_gates<L, Q + 1>(st, ang, qp, lane);
  }
}

__device__ __forceinline__ float redsum(float v) {
  v += shx<1>(v);
  v += shx<2>(v);
  v += shx<4>(v);
  v += shx<8>(v);
  v += shx<16>(v);
  v += __shfl_xor(v, 32, 64);
  return v;
}

// finish one <Z_q>: lane-parity sign, full-wave reduce, stash into outv on lane Q
template<int Q>
__device__ __forceinline__ void finish(const float* accs, float& outv, int lane) {
  if constexpr (Q < NQ) {
    constexpr unsigned RF  = MP.rf[Q];
    constexpr unsigned RLO = RF & 63u;
    float a = accs[Q];
    float sLn = (__popc((int)(RLO & (unsigned)lane)) & 1) ? -a : a;
    float t = redsum(sLn);
    if (lane == Q) outv = t;
    finish<Q + 1>(accs, outv, lane);
  }
}

__global__ __launch_bounds__(64, 3) void qtr_kernel(const float* __restrict__ x,
                                                    const float* __restrict__ W,
                                                    const float* __restrict__ qp,
                                                    float* __restrict__ out) {
  int b = blockIdx.x;
  int lane = threadIdx.x;

  // angles[q] = pi * tanh(dot(x[b], W[q])) — lane-parallel dot + butterfly reduce
  float xv = x[b * FEAT + lane];
  float ang[NQ];
  #pragma unroll
  for (int q = 0; q < NQ; ++q) {
    float prod = redsum(xv * W[q * FEAT + lane]);
    ang[q] = PI_F * tanhf(prod);
  }

  // |0...0>
  float2 st[64];
  #pragma unroll
  for (int r = 0; r < 64; ++r) st[r] = make_float2(0.f, 0.f);
  if (lane == 0) st[0].x = 1.f;

  do_gates<0, 0>(st, ang, qp, lane);

  // probabilities folded directly into 12 parity-signed partial sums
  float accs[NQ];
  #pragma unroll
  for (int q = 0; q < NQ; ++q) accs[q] = 0.f;
  #pragma unroll
  for (int r = 0; r < 64; ++r) {
    float p = st[r].x * st[r].x + st[r].y * st[r].y;
    #pragma unroll
    for (int q = 0; q < NQ; ++q) {
      // compile-time sign from register-bit parity of final measurement row
      const bool neg = ((__builtin_popcount(((MP.rf[q] >> 6) & 63u) & (unsigned)r)) & 1) != 0;
      accs[q] = neg ? (accs[q] - p) : (accs[q] + p);
    }
  }

  float outv = 0.f;
  finish<0>(accs, outv, lane);

  if (lane < NQ) out[b * NQ + lane] = outv;
}

}  // namespace

extern "C" void kernel_launch(void* const* d_in, const int* in_sizes, int n_in,
                              void* d_out, int out_size, void* d_ws, size_t ws_size,
                              hipStream_t stream) {
  const float* x  = (const float*)d_in[0];
  const float* W  = (const float*)d_in[1];
  const float* qp = (const float*)d_in[2];
  float* out = (float*)d_out;
  qtr_kernel<<<8192, 64, 0, stream>>>(x, W, qp, out);
}

// Round 3
// 206.332 us; speedup vs baseline: 1.5869x; 1.1660x over previous
//
#include <hip/hip_runtime.h>

namespace {

constexpr int NQ = 12;
constexpr int NL = 3;
constexpr int FEAT = 64;
constexpr float PI_F = 3.14159265358979323846f;

// ---- compile-time tracking of the deferred CNOT permutation (GF(2) linear map) ----
// Storage invariant: st_phys[p] = amp[i] with p = sigma(P(i)).
// Single-qubit gate on logical bit b pairs p and p ^ sigma(col_b(P)); the element with
// logical bit==0 is the one with parity(sigma(row_b(P^{-1})) & p) == 0.
// CNOT(c,t): col[bc] ^= col[bt]; rowinv[bt] ^= rowinv[bc]. sigma chosen to maximize
// the number of register-local gates (mask confined to the 6 register bits).
struct Maps {
  unsigned m[NL][NQ];   // pairing mask per (layer, qubit)
  unsigned rv[NL][NQ];  // parity row per (layer, qubit)
  unsigned rf[NQ];      // final parity rows for <Z_q>
  bool ok;
};

constexpr Maps compute_raw() {
  Maps mp{};
  unsigned col[NQ] = {}, row[NQ] = {};
  for (int b = 0; b < NQ; ++b) { col[b] = 1u << b; row[b] = 1u << b; }
  mp.ok = true;
  for (int L = 0; L < NL; ++L) {
    for (int q = 0; q < NQ; ++q) {
      mp.m[L][q]  = col[NQ - 1 - q];
      mp.rv[L][q] = row[NQ - 1 - q];
      unsigned x = mp.m[L][q] & mp.rv[L][q];
      int pc = 0;
      for (int i = 0; i < NQ; ++i) pc ^= (int)((x >> i) & 1u);
      if (pc != 1) mp.ok = false;  // pair must straddle logical 0/1
    }
    for (int q = 0; q < NQ; ++q) {
      int bc = NQ - 1 - q;
      int bt = NQ - 1 - ((q + 1) % NQ);
      col[bc] ^= col[bt];
      row[bt] ^= row[bc];
    }
  }
  for (int q = 0; q < NQ; ++q) mp.rf[q] = row[NQ - 1 - q];
  return mp;
}

constexpr int pc12(unsigned x) { int c = 0; for (int i = 0; i < 12; ++i) c += (int)((x >> i) & 1u); return c; }

constexpr unsigned pmask(unsigned m, const int* pos) {
  unsigned r = 0;
  for (int b = 0; b < 12; ++b) if ((m >> b) & 1u) r |= 1u << pos[b];
  return r;
}

constexpr Maps compute_maps() {
  Maps raw = compute_raw();
  // pick the 6 "register bits" S maximizing # of register-local gates
  unsigned bestS = 0xFC0u; int best = -1;
  for (unsigned S = 0; S < 4096; ++S) {
    if (pc12(S) != 6) continue;
    int cnt = 0;
    for (int L = 0; L < NL; ++L)
      for (int q = 0; q < NQ; ++q)
        if ((raw.m[L][q] & ~S) == 0u) ++cnt;
    if (cnt > best) { best = cnt; bestS = S; }
  }
  int pos[12] = {};
  int lo = 0, hi = 6;
  for (int b = 0; b < 12; ++b) {
    if ((bestS >> b) & 1u) pos[b] = hi++; else pos[b] = lo++;
  }
  Maps mp{};
  mp.ok = raw.ok;
  for (int L = 0; L < NL; ++L)
    for (int q = 0; q < NQ; ++q) {
      mp.m[L][q]  = pmask(raw.m[L][q], pos);
      mp.rv[L][q] = pmask(raw.rv[L][q], pos);
    }
  for (int q = 0; q < NQ; ++q) mp.rf[q] = pmask(raw.rf[q], pos);
  return mp;
}

constexpr Maps MP = compute_maps();
static_assert(MP.ok, "pairing invariant violated");

// xor-shuffle across lanes, compile-time mask. mask<32 -> ds_swizzle imm (no VALU).
// else one ds_bpermute with addr = lane4 ^ (MLO<<2) (xor is CSE'd per gate).
template<unsigned MLO>
__device__ __forceinline__ float shx(float v, int lane4) {
  if constexpr (MLO == 0u) {
    return v;
  } else if constexpr (MLO < 32u) {
    constexpr int off = (int)((MLO << 10) | 0x1fu);
    return __int_as_float(__builtin_amdgcn_ds_swizzle(__float_as_int(v), off));
  } else {
    int addr = lane4 ^ (int)(MLO << 2);
    return __int_as_float(__builtin_amdgcn_ds_bpermute(addr, __float_as_int(v)));
  }
}

template<bool REAL>
__device__ __forceinline__ float2 upd(float2 a, float2 p, float ar, float aiU, float brU, float b0i) {
  float2 o;
  if constexpr (REAL) {
    o.x = ar * a.x + brU * p.x;
    o.y = ar * a.y + brU * p.y;
  } else {
    o.x = ar * a.x - aiU * a.y + brU * p.x - b0i * p.y;
    o.y = ar * a.y + aiU * a.x + brU * p.y + b0i * p.x;
  }
  return o;
}

// Fused U = RZ(2*phihalf) * RY(2*ghalf); REAL drops the RZ (last layer: phases cancel in |amp|^2).
template<unsigned M, unsigned R, int NREG, bool REAL>
__device__ __forceinline__ void gate(float2* st, float ghalf, float phihalf, int lane, int lane4) {
  float s, c;
  __sincosf(ghalf, &s, &c);
  float ar, ai, b0r, b0i;
  if constexpr (REAL) {
    ar = c; ai = 0.f; b0r = -s; b0i = 0.f;
  } else {
    float sf, cf;
    __sincosf(phihalf, &sf, &cf);
    ar = c * cf; ai = -c * sf; b0r = -s * cf; b0i = s * sf;
  }
  constexpr unsigned MHI = (M >> 6) & 63u;
  constexpr unsigned MLO = M & 63u;
  constexpr unsigned RHI = (R >> 6) & 63u;
  constexpr unsigned RLO = R & 63u;
  float sL = (__popc((int)(RLO & (unsigned)lane)) & 1) ? -1.f : 1.f;
  float aiS = REAL ? 0.f : sL * ai;
  float brS = sL * b0r;
  if constexpr (MLO == 0u) {
    // register-local pairing
    constexpr unsigned TB = MHI & (~MHI + 1u);
    #pragma unroll
    for (int r = 0; r < NREG; ++r) {
      if ((r & (int)TB) == 0) {
        int r2 = r ^ (int)MHI;
        bool rp = (__builtin_popcount((unsigned)r & RHI) & 1) != 0;
        float aiU1 = rp ? -aiS : aiS;
        float brU1 = rp ? -brS : brS;
        float2 a = st[r], b = st[r2];
        st[r]  = upd<REAL>(a, b, ar, aiU1, brU1, b0i);
        st[r2] = upd<REAL>(b, a, ar, -aiU1, -brU1, b0i);  // partner parity opposite
      }
    }
  } else if constexpr (MHI == 0u) {
    // pure cross-lane pairing
    #pragma unroll
    for (int r = 0; r < NREG; ++r) {
      float2 p;
      p.x = shx<MLO>(st[r].x, lane4);
      p.y = shx<MLO>(st[r].y, lane4);
      bool rp = (__builtin_popcount((unsigned)r & RHI) & 1) != 0;
      float aiU = rp ? -aiS : aiS;
      float brU = rp ? -brS : brS;
      st[r] = upd<REAL>(st[r], p, ar, aiU, brU, b0i);
    }
  } else {
    // mixed: partner = other lane AND other register
    constexpr unsigned TB = MHI & (~MHI + 1u);
    #pragma unroll
    for (int r = 0; r < NREG; ++r) {
      if ((r & (int)TB) == 0) {
        int r2 = r ^ (int)MHI;
        float2 pa, pb;
        pa.x = shx<MLO>(st[r2].x, lane4);
        pa.y = shx<MLO>(st[r2].y, lane4);
        pb.x = shx<MLO>(st[r].x, lane4);
        pb.y = shx<MLO>(st[r].y, lane4);
        bool rp  = (__builtin_popcount((unsigned)r  & RHI) & 1) != 0;
        bool rp2 = (__builtin_popcount((unsigned)r2 & RHI) & 1) != 0;
        float aiU  = rp  ? -aiS : aiS;
        float brU  = rp  ? -brS : brS;
        float aiU2 = rp2 ? -aiS : aiS;
        float brU2 = rp2 ? -brS : brS;
        float2 a = st[r], b = st[r2];
        st[r]  = upd<REAL>(a, pa, ar, aiU,  brU,  b0i);
        st[r2] = upd<REAL>(b, pb, ar, aiU2, brU2, b0i);
      }
    }
  }
}

// ---- layer 0 on the sparse |0..0> state (all 12 gates commute) ----
// lane-bit gates act while support is a single register
template<int Q>
__device__ __forceinline__ void l0_lane(float2* st, const float* ang, const float* __restrict__ qp, int lane, int lane4) {
  if constexpr (Q < NQ) {
    constexpr unsigned M = MP.m[0][Q];
    if constexpr (M < 64u) {
      gate<M, MP.rv[0][Q], 1, false>(st, 0.5f * (ang[Q] + qp[Q * 2 + 0]), 0.5f * qp[Q * 2 + 1], lane, lane4);
    }
    l0_lane<Q + 1>(st, ang, qp, lane, lane4);
  }
}

// register-bit gates with doubling support; partner register starts at zero -> pure writes
template<int Q, unsigned DONE>
__device__ __forceinline__ void l0_reg(float2* st, const float* ang, const float* __restrict__ qp) {
  if constexpr (Q < NQ) {
    constexpr unsigned M = MP.m[0][Q];
    if constexpr (M >= 64u) {
      constexpr unsigned TB = (M >> 6) & 63u;
      float sh = 0.5f * (ang[Q] + qp[Q * 2 + 0]);
      float ph = 0.5f * qp[Q * 2 + 1];
      float s, c, sf, cf;
      __sincosf(sh, &s, &c);
      __sincosf(ph, &sf, &cf);
      float a0r = c * cf, a0i = -c * sf;  // U00 = c e^{-i phi}
      float b1r = s * cf, b1i = s * sf;   // U10 = s e^{+i phi}
      #pragma unroll
      for (int r = 0; r < 64; ++r) {
        if ((r & ~(int)DONE & 63) == 0) {  // r within current support
          float2 a = st[r];
          int r2 = r | (int)TB;
          st[r].x  = a0r * a.x - a0i * a.y;
          st[r].y  = a0r * a.y + a0i * a.x;
          st[r2].x = b1r * a.x - b1i * a.y;
          st[r2].y = b1r * a.y + b1i * a.x;
        }
      }
      l0_reg<Q + 1, DONE | TB>(st, ang, qp);
    } else {
      l0_reg<Q + 1, DONE>(st, ang, qp);
    }
  }
}

template<int L, int Q>
__device__ __forceinline__ void do_gates(float2* st, const float* ang, const float* __restrict__ qp, int lane, int lane4) {
  if constexpr (Q == NQ) {
    if constexpr (L + 1 < NL) do_gates<L + 1, 0>(st, ang, qp, lane, lane4);
  } else {
    constexpr bool REAL = (L == NL - 1);
    float th0 = qp[(L * NQ + Q) * 2 + 0];
    float ph = REAL ? 0.f : 0.5f * qp[(L * NQ + Q) * 2 + 1];
    gate<MP.m[L][Q], MP.rv[L][Q], 64, REAL>(st, 0.5f * (ang[Q] + th0), ph, lane, lane4);
    do_gates<L, Q + 1>(st, ang, qp, lane, lane4);
  }
}

__device__ __forceinline__ float redsum(float v, int lane4) {
  v += shx<1>(v, lane4);
  v += shx<2>(v, lane4);
  v += shx<4>(v, lane4);
  v += shx<8>(v, lane4);
  v += shx<16>(v, lane4);
  v += shx<32>(v, lane4);
  return v;
}

// finish one <Z_q>: lane-parity sign, full-wave reduce, stash into outv on lane Q
template<int Q>
__device__ __forceinline__ void finish(const float* accs, float& outv, int lane, int lane4) {
  if constexpr (Q < NQ) {
    constexpr unsigned RLO = MP.rf[Q] & 63u;
    float a = accs[Q];
    float sLn = (__popc((int)(RLO & (unsigned)lane)) & 1) ? -a : a;
    float t = redsum(sLn, lane4);
    if (lane == Q) outv = t;
    finish<Q + 1>(accs, outv, lane, lane4);
  }
}

__global__ __launch_bounds__(64, 2) void qtr_kernel(const float* __restrict__ x,
                                                    const float* __restrict__ W,
                                                    const float* __restrict__ qp,
                                                    float* __restrict__ out) {
  int b = blockIdx.x;
  int lane = threadIdx.x;
  int lane4 = lane << 2;

  // angles[q] = pi * tanh(dot(x[b], W[q]))
  float xv = x[b * FEAT + lane];
  float ang[NQ];
  #pragma unroll
  for (int q = 0; q < NQ; ++q) {
    float prod = redsum(xv * W[q * FEAT + lane], lane4);
    ang[q] = PI_F * tanhf(prod);
  }

  // sparse |0..0>: only st[0] is live until l0_reg writes every register exactly once
  float2 st[64];
  st[0].x = (lane == 0) ? 1.f : 0.f;
  st[0].y = 0.f;

  l0_lane<0>(st, ang, qp, lane, lane4);
  l0_reg<0, 0u>(st, ang, qp);
  do_gates<1, 0>(st, ang, qp, lane, lane4);

  // probabilities folded directly into 12 parity-signed partial sums
  float accs[NQ];
  #pragma unroll
  for (int q = 0; q < NQ; ++q) accs[q] = 0.f;
  #pragma unroll
  for (int r = 0; r < 64; ++r) {
    float p = st[r].x * st[r].x + st[r].y * st[r].y;
    #pragma unroll
    for (int q = 0; q < NQ; ++q) {
      const bool neg = ((__builtin_popcount(((MP.rf[q] >> 6) & 63u) & (unsigned)r)) & 1) != 0;
      accs[q] = neg ? (accs[q] - p) : (accs[q] + p);
    }
  }

  float outv = 0.f;
  finish<0>(accs, outv, lane, lane4);

  if (lane < NQ) out[b * NQ + lane] = outv;
}

}  // namespace

extern "C" void kernel_launch(void* const* d_in, const int* in_sizes, int n_in,
                              void* d_out, int out_size, void* d_ws, size_t ws_size,
                              hipStream_t stream) {
  const float* x  = (const float*)d_in[0];
  const float* W  = (const float*)d_in[1];
  const float* qp = (const float*)d_in[2];
  float* out = (float*)d_out;
  qtr_kernel<<<8192, 64, 0, stream>>>(x, W, qp, out);
}

// Round 4
// 161.262 us; speedup vs baseline: 2.0304x; 1.2795x over previous
//
#include <hip/hip_runtime.h>

namespace {

constexpr int NQ = 12;
constexpr int NL = 3;
constexpr int FEAT = 64;
constexpr float PI_F = 3.14159265358979323846f;

typedef float f2 __attribute__((ext_vector_type(2)));

// ---- compile-time tracking of the deferred CNOT permutation (GF(2) linear map) ----
// Storage invariant: st_phys[p] = amp[i] with p = sigma(P(i)).
// Single-qubit gate on logical bit b pairs p and p ^ sigma(col_b(P)); the element with
// logical bit==0 is the one with parity(sigma(row_b(P^{-1})) & p) == 0.
// CNOT(c,t): col[bc] ^= col[bt]; rowinv[bt] ^= rowinv[bc]. sigma chosen to maximize
// the number of register-local gates (mask confined to the 6 register bits).
struct Maps {
  unsigned m[NL][NQ];   // pairing mask per (layer, qubit)
  unsigned rv[NL][NQ];  // parity row per (layer, qubit)
  unsigned rf[NQ];      // final parity rows for <Z_q>
  bool ok;
};

constexpr Maps compute_raw() {
  Maps mp{};
  unsigned col[NQ] = {}, row[NQ] = {};
  for (int b = 0; b < NQ; ++b) { col[b] = 1u << b; row[b] = 1u << b; }
  mp.ok = true;
  for (int L = 0; L < NL; ++L) {
    for (int q = 0; q < NQ; ++q) {
      mp.m[L][q]  = col[NQ - 1 - q];
      mp.rv[L][q] = row[NQ - 1 - q];
      unsigned x = mp.m[L][q] & mp.rv[L][q];
      int pc = 0;
      for (int i = 0; i < NQ; ++i) pc ^= (int)((x >> i) & 1u);
      if (pc != 1) mp.ok = false;  // pair must straddle logical 0/1
    }
    for (int q = 0; q < NQ; ++q) {
      int bc = NQ - 1 - q;
      int bt = NQ - 1 - ((q + 1) % NQ);
      col[bc] ^= col[bt];
      row[bt] ^= row[bc];
    }
  }
  for (int q = 0; q < NQ; ++q) mp.rf[q] = row[NQ - 1 - q];
  return mp;
}

constexpr int pc12(unsigned x) { int c = 0; for (int i = 0; i < 12; ++i) c += (int)((x >> i) & 1u); return c; }

constexpr unsigned pmask(unsigned m, const int* pos) {
  unsigned r = 0;
  for (int b = 0; b < 12; ++b) if ((m >> b) & 1u) r |= 1u << pos[b];
  return r;
}

constexpr Maps compute_maps() {
  Maps raw = compute_raw();
  // pick the 6 "register bits" S maximizing # of register-local gates
  unsigned bestS = 0xFC0u; int best = -1;
  for (unsigned S = 0; S < 4096; ++S) {
    if (pc12(S) != 6) continue;
    int cnt = 0;
    for (int L = 0; L < NL; ++L)
      for (int q = 0; q < NQ; ++q)
        if ((raw.m[L][q] & ~S) == 0u) ++cnt;
    if (cnt > best) { best = cnt; bestS = S; }
  }
  int pos[12] = {};
  int lo = 0, hi = 6;
  for (int b = 0; b < 12; ++b) {
    if ((bestS >> b) & 1u) pos[b] = hi++; else pos[b] = lo++;
  }
  Maps mp{};
  mp.ok = raw.ok;
  for (int L = 0; L < NL; ++L)
    for (int q = 0; q < NQ; ++q) {
      mp.m[L][q]  = pmask(raw.m[L][q], pos);
      mp.rv[L][q] = pmask(raw.rv[L][q], pos);
    }
  for (int q = 0; q < NQ; ++q) mp.rf[q] = pmask(raw.rf[q], pos);
  return mp;
}

constexpr Maps MP = compute_maps();
static_assert(MP.ok, "pairing invariant violated");

// ---- packed FP32 primitives (VOP3P) — single-instruction pure asm, schedulable ----
// d = (u.lo*a.lo, u.lo*a.hi)
__device__ __forceinline__ f2 pk_mul_bl(f2 a, f2 u) {
  f2 d;
  asm("v_pk_mul_f32 %0, %1, %2 op_sel:[0,0] op_sel_hi:[1,0]" : "=v"(d) : "v"(a), "v"(u));
  return d;
}
// d = c + u.hi*(-a.hi, +a.lo)   (complex "i" rotation term, + variant)
__device__ __forceinline__ f2 pk_fma_rot_p(f2 a, f2 u, f2 c) {
  f2 d;
  asm("v_pk_fma_f32 %0, %1, %2, %3 op_sel:[1,1,0] op_sel_hi:[0,1,1] neg_lo:[1,0,0]"
      : "=v"(d) : "v"(a), "v"(u), "v"(c));
  return d;
}
// d = c + u.hi*(+a.hi, -a.lo)   (rotation with u.hi negated)
__device__ __forceinline__ f2 pk_fma_rot_m(f2 a, f2 u, f2 c) {
  f2 d;
  asm("v_pk_fma_f32 %0, %1, %2, %3 op_sel:[1,1,0] op_sel_hi:[0,1,1] neg_hi:[1,0,0]"
      : "=v"(d) : "v"(a), "v"(u), "v"(c));
  return d;
}
// d = c + v.lo*(p.lo, p.hi)
__device__ __forceinline__ f2 pk_fma_bl_p(f2 p, f2 v, f2 c) {
  f2 d;
  asm("v_pk_fma_f32 %0, %1, %2, %3 op_sel:[0,0,0] op_sel_hi:[1,0,1]"
      : "=v"(d) : "v"(p), "v"(v), "v"(c));
  return d;
}
// d = c - v.lo*(p.lo, p.hi)
__device__ __forceinline__ f2 pk_fma_bl_m(f2 p, f2 v, f2 c) {
  f2 d;
  asm("v_pk_fma_f32 %0, %1, %2, %3 op_sel:[0,0,0] op_sel_hi:[1,0,1] neg_lo:[0,1,0] neg_hi:[0,1,0]"
      : "=v"(d) : "v"(p), "v"(v), "v"(c));
  return d;
}
// plain packed mul / fma (default modifiers)
__device__ __forceinline__ f2 pk_mul_d(f2 a, f2 b) {
  f2 d;
  asm("v_pk_mul_f32 %0, %1, %2" : "=v"(d) : "v"(a), "v"(b));
  return d;
}
__device__ __forceinline__ f2 pk_fma_d(f2 a, f2 b, f2 c) {
  f2 d;
  asm("v_pk_fma_f32 %0, %1, %2, %3" : "=v"(d) : "v"(a), "v"(b), "v"(c));
  return d;
}

// complex update o = u*a + v*p; u=(ar,aiU'), v=(brU',b0i); _p/_m = register parity variants
template<bool REAL>
__device__ __forceinline__ f2 updp(f2 a, f2 p, f2 u, f2 v) {
  if constexpr (REAL) return pk_fma_bl_p(p, v, pk_mul_bl(a, u));
  else return pk_fma_rot_p(p, v, pk_fma_bl_p(p, v, pk_fma_rot_p(a, u, pk_mul_bl(a, u))));
}
template<bool REAL>
__device__ __forceinline__ f2 updm(f2 a, f2 p, f2 u, f2 v) {
  if constexpr (REAL) return pk_fma_bl_m(p, v, pk_mul_bl(a, u));
  else return pk_fma_rot_p(p, v, pk_fma_bl_m(p, v, pk_fma_rot_m(a, u, pk_mul_bl(a, u))));
}

// xor-shuffle across lanes, compile-time mask. mask<32 -> ds_swizzle imm (no VALU).
// else one ds_bpermute with addr = lane4 ^ (MLO<<2).
template<unsigned MLO>
__device__ __forceinline__ float shx(float v, int lane4) {
  if constexpr (MLO == 0u) {
    return v;
  } else if constexpr (MLO < 32u) {
    constexpr int off = (int)((MLO << 10) | 0x1fu);
    return __int_as_float(__builtin_amdgcn_ds_swizzle(__float_as_int(v), off));
  } else {
    int addr = lane4 ^ (int)(MLO << 2);
    return __int_as_float(__builtin_amdgcn_ds_bpermute(addr, __float_as_int(v)));
  }
}

// Fused U = RZ(2*phihalf) * RY(2*ghalf); REAL drops the RZ (last layer: phases cancel in |amp|^2).
template<unsigned M, unsigned R, int NREG, bool REAL>
__device__ __forceinline__ void gate(f2* st, float ghalf, float phihalf, int lane, int lane4) {
  float s, c;
  __sincosf(ghalf, &s, &c);
  constexpr unsigned MHI = (M >> 6) & 63u;
  constexpr unsigned MLO = M & 63u;
  constexpr unsigned RHI = (R >> 6) & 63u;
  constexpr unsigned RLO = R & 63u;
  float sL = (__popc((int)(RLO & (unsigned)lane)) & 1) ? -1.f : 1.f;
  f2 u, v;
  if constexpr (REAL) {
    u.x = c;       u.y = 0.f;
    v.x = -s * sL; v.y = 0.f;
  } else {
    float sf, cf;
    __sincosf(phihalf, &sf, &cf);
    u.x = c * cf;         u.y = (-c * sf) * sL;
    v.x = (-s * cf) * sL; v.y = s * sf;
  }
  if constexpr (MLO == 0u) {
    // register-local pairing; parity(MHI&RHI)==1 -> partner parity opposite
    constexpr unsigned TB = MHI & (~MHI + 1u);
    #pragma unroll
    for (int r = 0; r < NREG; ++r) {
      if ((r & (int)TB) == 0) {
        int r2 = r ^ (int)MHI;
        const bool rp = ((__builtin_popcount((unsigned)r & RHI)) & 1) != 0;
        f2 a = st[r], b = st[r2];
        st[r]  = rp ? updm<REAL>(a, b, u, v) : updp<REAL>(a, b, u, v);
        st[r2] = rp ? updp<REAL>(b, a, u, v) : updm<REAL>(b, a, u, v);
      }
    }
  } else if constexpr (MHI == 0u) {
    // pure cross-lane pairing
    #pragma unroll
    for (int r = 0; r < NREG; ++r) {
      f2 p;
      p.x = shx<MLO>(st[r].x, lane4);
      p.y = shx<MLO>(st[r].y, lane4);
      const bool rp = ((__builtin_popcount((unsigned)r & RHI)) & 1) != 0;
      st[r] = rp ? updm<REAL>(st[r], p, u, v) : updp<REAL>(st[r], p, u, v);
    }
  } else {
    // mixed: partner = other lane AND other register
    constexpr unsigned TB = MHI & (~MHI + 1u);
    #pragma unroll
    for (int r = 0; r < NREG; ++r) {
      if ((r & (int)TB) == 0) {
        int r2 = r ^ (int)MHI;
        f2 pa, pb;
        pa.x = shx<MLO>(st[r2].x, lane4);
        pa.y = shx<MLO>(st[r2].y, lane4);
        pb.x = shx<MLO>(st[r].x, lane4);
        pb.y = shx<MLO>(st[r].y, lane4);
        const bool rp  = ((__builtin_popcount((unsigned)r  & RHI)) & 1) != 0;
        const bool rp2 = ((__builtin_popcount((unsigned)r2 & RHI)) & 1) != 0;
        f2 a = st[r], b = st[r2];
        st[r]  = rp  ? updm<REAL>(a, pa, u, v) : updp<REAL>(a, pa, u, v);
        st[r2] = rp2 ? updm<REAL>(b, pb, u, v) : updp<REAL>(b, pb, u, v);
      }
    }
  }
}

// ---- layer 0 on the sparse |0..0> state (all 12 gates commute) ----
// lane-bit gates act while support is a single register
template<int Q>
__device__ __forceinline__ void l0_lane(f2* st, const float* ang, const float* __restrict__ qp, int lane, int lane4) {
  if constexpr (Q < NQ) {
    constexpr unsigned M = MP.m[0][Q];
    if constexpr (M < 64u) {
      gate<M, MP.rv[0][Q], 1, false>(st, 0.5f * (ang[Q] + qp[Q * 2 + 0]), 0.5f * qp[Q * 2 + 1], lane, lane4);
    }
    l0_lane<Q + 1>(st, ang, qp, lane, lane4);
  }
}

// register-bit gates with doubling support; partner register starts at zero -> pure writes
template<int Q, unsigned DONE>
__device__ __forceinline__ void l0_reg(f2* st, const float* ang, const float* __restrict__ qp) {
  if constexpr (Q < NQ) {
    constexpr unsigned M = MP.m[0][Q];
    if constexpr (M >= 64u) {
      constexpr unsigned TB = (M >> 6) & 63u;
      float sh = 0.5f * (ang[Q] + qp[Q * 2 + 0]);
      float ph = 0.5f * qp[Q * 2 + 1];
      float s, c, sf, cf;
      __sincosf(sh, &s, &c);
      __sincosf(ph, &sf, &cf);
      f2 u0; u0.x = c * cf; u0.y = -c * sf;  // U00 = c e^{-i phi}
      f2 u1; u1.x = s * cf; u1.y = s * sf;   // U10 = s e^{+i phi}
      #pragma unroll
      for (int r = 0; r < 64; ++r) {
        if ((r & ~(int)DONE & 63) == 0) {  // r within current support
          f2 a = st[r];
          int r2 = r | (int)TB;
          st[r]  = pk_fma_rot_p(a, u0, pk_mul_bl(a, u0));
          st[r2] = pk_fma_rot_p(a, u1, pk_mul_bl(a, u1));
        }
      }
      l0_reg<Q + 1, DONE | TB>(st, ang, qp);
    } else {
      l0_reg<Q + 1, DONE>(st, ang, qp);
    }
  }
}

template<int L, int Q>
__device__ __forceinline__ void do_gates(f2* st, const float* ang, const float* __restrict__ qp, int lane, int lane4) {
  if constexpr (Q == NQ) {
    if constexpr (L + 1 < NL) do_gates<L + 1, 0>(st, ang, qp, lane, lane4);
  } else {
    constexpr bool REAL = (L == NL - 1);
    float th0 = qp[(L * NQ + Q) * 2 + 0];
    float ph = REAL ? 0.f : 0.5f * qp[(L * NQ + Q) * 2 + 1];
    gate<MP.m[L][Q], MP.rv[L][Q], 64, REAL>(st, 0.5f * (ang[Q] + th0), ph, lane, lane4);
    do_gates<L, Q + 1>(st, ang, qp, lane, lane4);
  }
}

__device__ __forceinline__ float redsum(float v, int lane4) {
  v += shx<1>(v, lane4);
  v += shx<2>(v, lane4);
  v += shx<4>(v, lane4);
  v += shx<8>(v, lane4);
  v += shx<16>(v, lane4);
  v += shx<32>(v, lane4);
  return v;
}

__device__ __forceinline__ float fast_tanh(float x) {
  float e = __expf(2.f * x);
  float r = __builtin_amdgcn_rcpf(e + 1.f);
  return 1.f - 2.f * r;
}

// finish one <Z_q>: lane-parity sign, full-wave reduce, stash into outv on lane Q
template<int Q>
__device__ __forceinline__ void finish(const f2* acc6, float& outv, int lane, int lane4) {
  if constexpr (Q < NQ) {
    constexpr unsigned RLO = MP.rf[Q] & 63u;
    float a = (Q & 1) ? acc6[Q / 2].y : acc6[Q / 2].x;
    float sLn = (__popc((int)(RLO & (unsigned)lane)) & 1) ? -a : a;
    float t = redsum(sLn, lane4);
    if (lane == Q) outv = t;
    finish<Q + 1>(acc6, outv, lane, lane4);
  }
}

__global__ __launch_bounds__(64, 2) void qtr_kernel(const float* __restrict__ x,
                                                    const float* __restrict__ W,
                                                    const float* __restrict__ qp,
                                                    float* __restrict__ out) {
  int b = blockIdx.x;
  int lane = threadIdx.x;
  int lane4 = lane << 2;

  // angles[q] = pi * tanh(dot(x[b], W[q]))
  float xv = x[b * FEAT + lane];
  float ang[NQ];
  #pragma unroll
  for (int q = 0; q < NQ; ++q) {
    float prod = redsum(xv * W[q * FEAT + lane], lane4);
    ang[q] = PI_F * fast_tanh(prod);
  }

  // sparse |0..0>: only st[0] is live until l0_reg writes every register exactly once
  f2 st[64];
  st[0].x = (lane == 0) ? 1.f : 0.f;
  st[0].y = 0.f;

  l0_lane<0>(st, ang, qp, lane, lane4);
  l0_reg<0, 0u>(st, ang, qp);
  do_gates<1, 0>(st, ang, qp, lane, lane4);

  // probabilities folded into 6 packed parity-signed accumulators (acc6[j] = (acc_{2j}, acc_{2j+1}))
  f2 acc6[6];
  #pragma unroll
  for (int j = 0; j < 6; ++j) { acc6[j].x = 0.f; acc6[j].y = 0.f; }
  #pragma unroll
  for (int r = 0; r < 64; ++r) {
    f2 q2 = pk_mul_d(st[r], st[r]);   // (re^2, im^2)
    float p = q2.x + q2.y;
    f2 pp; pp.x = p; pp.y = p;
    #pragma unroll
    for (int j = 0; j < 6; ++j) {
      const bool n0 = ((__builtin_popcount(((MP.rf[2 * j]     >> 6) & 63u) & (unsigned)r)) & 1) != 0;
      const bool n1 = ((__builtin_popcount(((MP.rf[2 * j + 1] >> 6) & 63u) & (unsigned)r)) & 1) != 0;
      f2 sg; sg.x = n0 ? -1.f : 1.f; sg.y = n1 ? -1.f : 1.f;  // folds to 4 hoisted constant pairs
      acc6[j] = pk_fma_d(pp, sg, acc6[j]);
    }
  }

  float outv = 0.f;
  finish<0>(acc6, outv, lane, lane4);

  if (lane < NQ) out[b * NQ + lane] = outv;
}

}  // namespace

extern "C" void kernel_launch(void* const* d_in, const int* in_sizes, int n_in,
                              void* d_out, int out_size, void* d_ws, size_t ws_size,
                              hipStream_t stream) {
  const float* x  = (const float*)d_in[0];
  const float* W  = (const float*)d_in[1];
  const float* qp = (const float*)d_in[2];
  float* out = (float*)d_out;
  qtr_kernel<<<8192, 64, 0, stream>>>(x, W, qp, out);
}

// Round 6
// 135.466 us; speedup vs baseline: 2.4170x; 1.1904x over previous
//
#include <hip/hip_runtime.h>

namespace {

constexpr int NQ = 12;
constexpr int NL = 3;
constexpr int FEAT = 64;
constexpr float PI_F = 3.14159265358979323846f;

typedef float f2 __attribute__((ext_vector_type(2)));

// ============================ constexpr GF(2) toolkit ============================
constexpr int par12(unsigned x) { int p = 0; for (int i = 0; i < 12; ++i) p ^= (int)((x >> i) & 1u); return p; }
constexpr int lead12(unsigned x) { for (int k = 11; k >= 0; --k) if ((x >> k) & 1u) return k; return -1; }

// echelon basis kept sorted by leading bit DESCENDING -> single-pass reduce is exact
struct Ech { unsigned v[16]; int n; };
constexpr unsigned ech_reduce(const Ech& E, unsigned x) {
  for (int i = 0; i < E.n; ++i) {
    int lb = lead12(E.v[i]);
    if (lb >= 0 && ((x >> lb) & 1u)) x ^= E.v[i];
  }
  return x;
}
constexpr bool ech_add(Ech& E, unsigned x) {
  unsigned r = ech_reduce(E, x);
  if (!r) return false;
  int lb = lead12(r);
  int pos = E.n;
  for (int i = 0; i < E.n; ++i) { if (lead12(E.v[i]) < lb) { pos = i; break; } }
  for (int i = E.n; i > pos; --i) E.v[i] = E.v[i - 1];
  E.v[pos] = r;
  E.n++;
  return true;
}

constexpr unsigned apmat(const unsigned* rows, unsigned v) {
  unsigned o = 0; for (int k = 0; k < 12; ++k) if (par12(rows[k] & v)) o |= 1u << k; return o;
}
constexpr bool inv12(const unsigned* in, unsigned* out) {
  unsigned a[12] = {}, b[12] = {};
  for (int k = 0; k < 12; ++k) { a[k] = in[k]; b[k] = 1u << k; }
  for (int c = 0; c < 12; ++c) {
    int p = -1;
    for (int r = c; r < 12; ++r) if ((a[r] >> c) & 1u) { p = r; break; }
    if (p < 0) return false;
    unsigned t = a[c]; a[c] = a[p]; a[p] = t; t = b[c]; b[c] = b[p]; b[p] = t;
    for (int r = 0; r < 12; ++r) if (r != c && ((a[r] >> c) & 1u)) { a[r] ^= a[c]; b[r] ^= b[c]; }
  }
  for (int k = 0; k < 12; ++k) out[k] = b[k];
  return true;
}
constexpr unsigned dropb(unsigned x, int t) {  // remove bit t, shift higher bits down (11-bit result)
  unsigned lm = (1u << t) - 1u;
  return (x & lm) | ((x >> 1) & (0x7FFu & ~lm));
}

// ============ logical circuit tracking (deferred CNOT ring, verified r1-r4) ============
// qubit q <-> logical bit 11-q. m = pairing mask (col of P); rv = parity row (row of P^-1).
struct Logical {
  unsigned m[NL][NQ], rv[NL][NQ], rf[NQ];
  bool ok;
};
constexpr Logical compute_raw() {
  Logical mp{};
  unsigned col[NQ] = {}, row[NQ] = {};
  for (int b = 0; b < NQ; ++b) { col[b] = 1u << b; row[b] = 1u << b; }
  mp.ok = true;
  for (int L = 0; L < NL; ++L) {
    for (int q = 0; q < NQ; ++q) {
      mp.m[L][q]  = col[NQ - 1 - q];
      mp.rv[L][q] = row[NQ - 1 - q];
      if (par12(mp.m[L][q] & mp.rv[L][q]) != 1) mp.ok = false;
    }
    for (int q = 0; q < NQ; ++q) {
      int bc = NQ - 1 - q;
      int bt = NQ - 1 - ((q + 1) % NQ);
      col[bc] ^= col[bt];
      row[bt] ^= row[bc];
    }
  }
  for (int q = 0; q < NQ; ++q) mp.rf[q] = row[NQ - 1 - q];
  return mp;
}

// ============================ phase/remap plan ============================
// Storage index p: bits [0..5] = lane, [6..11] = register. 5 epochs: l0 (identity), then 4
// phases (layer1 a/b, layer2 a/b) each with a labeling making all 6 gate masks register-local.
// Epoch transition = 2-stage wave-local LDS permutation (16KB, half the state per stage).
// Chunk invariant: old-half {r: bit cb == s} maps exactly onto new-half {rp: bit cb == s},
// so each stage writes then overwrites the SAME physical register set (no aliasing).
struct Plan {
  unsigned l0m[NQ], l0r[NQ];
  unsigned gm[4][6];      // storage mask (low6 == 0)
  unsigned gr[4][6];      // storage parity row (12-bit)
  unsigned rf[NQ];        // final measurement parity rows (final labeling)
  unsigned phi[4][6];     // old-storage image of new lane basis (bit 6+cb == 0)
  unsigned coffE[4][64];  // per-new-reg old-entry offset (11-bit, bit 6+cb dropped)
  int cb[4];              // chunk reg-bit (same bit in old and new labeling)
  bool ok;
};

constexpr bool findH(const Ech& G, unsigned rho, unsigned& out) {
  for (unsigned t = 0; t < 12; ++t) {
    unsigned v = 1u << t;
    if (par12(v & rho) == 0 && ech_reduce(G, v)) { out = v; return true; }
  }
  for (unsigned v = 1; v < 4096u; ++v) {
    if (par12(v & rho) == 0 && ech_reduce(G, v)) { out = v; return true; }
  }
  return false;
}

constexpr Plan build_plan() {
  Logical raw = compute_raw();
  Plan P{};
  P.ok = raw.ok;
  for (int q = 0; q < NQ; ++q) { P.l0m[q] = raw.m[0][q]; P.l0r[q] = raw.rv[0][q]; }
  unsigned fwd[12] = {}, invc[12] = {};
  for (int k = 0; k < 12; ++k) { fwd[k] = 1u << k; invc[k] = 1u << k; }
  for (int ph = 0; ph < 4; ++ph) {
    const int L = 1 + ph / 2, q0 = (ph % 2) * 6;
    unsigned ml[6] = {};
    for (int i = 0; i < 6; ++i) ml[i] = raw.m[L][q0 + i];
    bool done = false;
    for (int cbi = 5; cbi >= 0 && !done; --cbi) {
      unsigned rho = fwd[6 + cbi];
      bool bad = false;
      // uc = chunk-carrying reg basis vector (non-orthogonal to rho); prefer a mask
      int idx = -1;
      for (int i = 0; i < 6; ++i) if (par12(ml[i] & rho)) { idx = i; break; }
      unsigned uc = 0;
      Ech W{};  // echelon of rho-perp components of masks
      if (idx >= 0) {
        uc = ml[idx];
        for (int i = 0; i < 6; ++i) {
          if (i == idx) continue;
          unsigned w = par12(ml[i] & rho) ? (ml[i] ^ uc) : ml[i];
          ech_add(W, w);  // dependent -> ignored
        }
        if (W.n > 5) bad = true;
      } else {
        for (int i = 0; i < 6; ++i) ech_add(W, ml[i]);
        if (W.n > 5) bad = true;  // all 6 dims inside the hyperplane: this cb unusable
        if (!bad) {
          bool got = false;
          for (unsigned t = 0; t < 12 && !got; ++t) {
            unsigned v = 1u << t;
            if (par12(v & rho)) { uc = v; got = true; }
          }
          if (!got) bad = true;
        }
      }
      if (bad) continue;
      Ech G{};
      for (int i = 0; i < W.n && !bad; ++i) if (!ech_add(G, W.v[i])) bad = true;
      if (!bad && !ech_add(G, uc)) bad = true;
      if (bad) continue;
      unsigned regH[5] = {};
      int nH = W.n;
      for (int i = 0; i < nH; ++i) regH[i] = W.v[i];
      for (int slot = nH; slot < 5 && !bad; ++slot) {
        unsigned v = 0;
        if (!findH(G, rho, v)) { bad = true; break; }
        regH[slot] = v; ech_add(G, v);
      }
      if (bad) continue;
      // lane basis: prefer old lane columns (identity read base -> clean banks)
      unsigned lam[6] = {};
      for (int j = 0; j < 6 && !bad; ++j) {
        unsigned cand = invc[j];
        if (par12(cand & rho) != 0 || !ech_reduce(G, cand)) {
          if (!findH(G, rho, cand)) { bad = true; break; }
        }
        lam[j] = cand; ech_add(G, cand);
      }
      if (bad) continue;
      // assemble new labeling columns; chunk vector at reg position cbi
      unsigned ncols[12] = {};
      for (int j = 0; j < 6; ++j) ncols[j] = lam[j];
      {
        int w = 0;
        for (int k = 0; k < 6; ++k) ncols[6 + k] = (k == cbi) ? uc : regH[w++];
      }
      unsigned Mrows[12] = {};
      for (int k = 0; k < 12; ++k) {
        unsigned r = 0;
        for (int j = 0; j < 12; ++j) r |= ((ncols[j] >> k) & 1u) << j;
        Mrows[k] = r;
      }
      unsigned fnew[12] = {};
      if (!inv12(Mrows, fnew)) continue;
      // validate
      bool okp = true;
      unsigned gmv[6] = {}, grv[6] = {};
      for (int i = 0; i < 6 && okp; ++i) {
        unsigned SM = apmat(fnew, ml[i]);
        if (SM & 63u) okp = false;
        unsigned sg = 0;
        for (int k = 0; k < 12; ++k) if (par12(raw.rv[L][q0 + i] & ncols[k])) sg |= 1u << k;
        if (par12(SM & sg) != 1) okp = false;
        gmv[i] = SM; grv[i] = sg;
      }
      unsigned phj[6] = {}, Ust[6] = {};
      for (int j = 0; j < 6 && okp; ++j) {
        phj[j] = apmat(fwd, lam[j]);
        if ((phj[j] >> (6 + cbi)) & 1u) okp = false;
      }
      for (int k = 0; k < 6 && okp; ++k) {
        Ust[k] = apmat(fwd, ncols[6 + k]);
        if (((Ust[k] >> (6 + cbi)) & 1u) != (unsigned)(k == cbi ? 1 : 0)) okp = false;
      }
      if (!okp) continue;
      // record
      P.cb[ph] = cbi;
      for (int j = 0; j < 6; ++j) P.phi[ph][j] = phj[j];
      for (int rp = 0; rp < 64; ++rp) {
        unsigned psi = 0;
        for (int k = 0; k < 6; ++k) if ((rp >> k) & 1) psi ^= Ust[k];
        P.coffE[ph][rp] = dropb(psi, 6 + cbi);
      }
      for (int i = 0; i < 6; ++i) { P.gm[ph][i] = gmv[i]; P.gr[ph][i] = grv[i]; }
      for (int k = 0; k < 12; ++k) { fwd[k] = fnew[k]; invc[k] = ncols[k]; }
      done = true;
    }
    if (!done) { P.ok = false; return P; }
  }
  for (int q = 0; q < NQ; ++q) {
    unsigned sg = 0;
    for (int k = 0; k < 12; ++k) if (par12(raw.rf[q] & invc[k])) sg |= 1u << k;
    P.rf[q] = sg;
  }
  return P;
}

constexpr Plan PLAN = build_plan();
static_assert(PLAN.ok, "plan construction failed");

// ============================ packed FP32 primitives ============================
__device__ __forceinline__ f2 pk_mul_bl(f2 a, f2 u) {
  f2 d;
  asm("v_pk_mul_f32 %0, %1, %2 op_sel:[0,0] op_sel_hi:[1,0]" : "=v"(d) : "v"(a), "v"(u));
  return d;
}
__device__ __forceinline__ f2 pk_fma_rot_p(f2 a, f2 u, f2 c) {
  f2 d;
  asm("v_pk_fma_f32 %0, %1, %2, %3 op_sel:[1,1,0] op_sel_hi:[0,1,1] neg_lo:[1,0,0]"
      : "=v"(d) : "v"(a), "v"(u), "v"(c));
  return d;
}
__device__ __forceinline__ f2 pk_fma_rot_m(f2 a, f2 u, f2 c) {
  f2 d;
  asm("v_pk_fma_f32 %0, %1, %2, %3 op_sel:[1,1,0] op_sel_hi:[0,1,1] neg_hi:[1,0,0]"
      : "=v"(d) : "v"(a), "v"(u), "v"(c));
  return d;
}
__device__ __forceinline__ f2 pk_fma_bl_p(f2 p, f2 v, f2 c) {
  f2 d;
  asm("v_pk_fma_f32 %0, %1, %2, %3 op_sel:[0,0,0] op_sel_hi:[1,0,1]"
      : "=v"(d) : "v"(p), "v"(v), "v"(c));
  return d;
}
__device__ __forceinline__ f2 pk_fma_bl_m(f2 p, f2 v, f2 c) {
  f2 d;
  asm("v_pk_fma_f32 %0, %1, %2, %3 op_sel:[0,0,0] op_sel_hi:[1,0,1] neg_lo:[0,1,0] neg_hi:[0,1,0]"
      : "=v"(d) : "v"(p), "v"(v), "v"(c));
  return d;
}
__device__ __forceinline__ f2 pk_mul_d(f2 a, f2 b) {
  f2 d;
  asm("v_pk_mul_f32 %0, %1, %2" : "=v"(d) : "v"(a), "v"(b));
  return d;
}
__device__ __forceinline__ f2 pk_fma_d(f2 a, f2 b, f2 c) {
  f2 d;
  asm("v_pk_fma_f32 %0, %1, %2, %3" : "=v"(d) : "v"(a), "v"(b), "v"(c));
  return d;
}

template<bool REAL>
__device__ __forceinline__ f2 updp(f2 a, f2 p, f2 u, f2 v) {
  if constexpr (REAL) return pk_fma_bl_p(p, v, pk_mul_bl(a, u));
  else return pk_fma_rot_p(p, v, pk_fma_bl_p(p, v, pk_fma_rot_p(a, u, pk_mul_bl(a, u))));
}
template<bool REAL>
__device__ __forceinline__ f2 updm(f2 a, f2 p, f2 u, f2 v) {
  if constexpr (REAL) return pk_fma_bl_m(p, v, pk_mul_bl(a, u));
  else return pk_fma_rot_p(p, v, pk_fma_bl_m(p, v, pk_fma_rot_m(a, u, pk_mul_bl(a, u))));
}

// xor-shuffle (remaining uses: l0 lane gates + reductions)
template<unsigned MLO>
__device__ __forceinline__ float shx(float v, int lane4) {
  if constexpr (MLO == 0u) {
    return v;
  } else if constexpr (MLO < 32u) {
    constexpr int off = (int)((MLO << 10) | 0x1fu);
    return __int_as_float(__builtin_amdgcn_ds_swizzle(__float_as_int(v), off));
  } else {
    int addr = lane4 ^ (int)(MLO << 2);
    return __int_as_float(__builtin_amdgcn_ds_bpermute(addr, __float_as_int(v)));
  }
}

// Fused U = RZ(2*phihalf) * RY(2*ghalf); REAL drops RZ (last layer, phases cancel in |amp|^2).
template<unsigned M, unsigned R, int NREG, bool REAL>
__device__ __forceinline__ void gate(f2* st, float ghalf, float phihalf, int lane, int lane4) {
  float s, c;
  __sincosf(ghalf, &s, &c);
  constexpr unsigned MHI = (M >> 6) & 63u;
  constexpr unsigned MLO = M & 63u;
  constexpr unsigned RHI = (R >> 6) & 63u;
  constexpr unsigned RLO = R & 63u;
  float sL = (__popc((int)(RLO & (unsigned)lane)) & 1) ? -1.f : 1.f;
  f2 u, v;
  if constexpr (REAL) {
    u.x = c;       u.y = 0.f;
    v.x = -s * sL; v.y = 0.f;
  } else {
    float sf, cf;
    __sincosf(phihalf, &sf, &cf);
    u.x = c * cf;         u.y = (-c * sf) * sL;
    v.x = (-s * cf) * sL; v.y = s * sf;
  }
  if constexpr (MLO == 0u) {
    constexpr unsigned TB = MHI & (~MHI + 1u);
    #pragma unroll
    for (int r = 0; r < NREG; ++r) {
      if ((r & (int)TB) == 0) {
        int r2 = r ^ (int)MHI;
        const bool rp = ((__builtin_popcount((unsigned)r & RHI)) & 1) != 0;
        f2 a = st[r], b = st[r2];
        st[r]  = rp ? updm<REAL>(a, b, u, v) : updp<REAL>(a, b, u, v);
        st[r2] = rp ? updp<REAL>(b, a, u, v) : updm<REAL>(b, a, u, v);
      }
    }
  } else {
    #pragma unroll
    for (int r = 0; r < NREG; ++r) {
      f2 p;
      p.x = shx<MLO>(st[r].x, lane4);
      p.y = shx<MLO>(st[r].y, lane4);
      const bool rp = ((__builtin_popcount((unsigned)r & RHI)) & 1) != 0;
      st[r] = rp ? updm<REAL>(st[r], p, u, v) : updp<REAL>(st[r], p, u, v);
    }
  }
}

// ---- layer 0 on sparse |0..0> (identity labeling; all masks single-bit) ----
template<int Q>
__device__ __forceinline__ void l0_lane(f2* st, const float* ang, const float* __restrict__ qp, int lane, int lane4) {
  if constexpr (Q < NQ) {
    constexpr unsigned M = PLAN.l0m[Q];
    if constexpr (M < 64u) {
      gate<M, PLAN.l0r[Q], 1, false>(st, 0.5f * (ang[Q] + qp[Q * 2 + 0]), 0.5f * qp[Q * 2 + 1], lane, lane4);
    }
    l0_lane<Q + 1>(st, ang, qp, lane, lane4);
  }
}
template<int Q, unsigned DONE>
__device__ __forceinline__ void l0_reg(f2* st, const float* ang, const float* __restrict__ qp) {
  if constexpr (Q < NQ) {
    constexpr unsigned M = PLAN.l0m[Q];
    if constexpr (M >= 64u) {
      constexpr unsigned TB = (M >> 6) & 63u;
      float sh = 0.5f * (ang[Q] + qp[Q * 2 + 0]);
      float ph = 0.5f * qp[Q * 2 + 1];
      float s, c, sf, cf;
      __sincosf(sh, &s, &c);
      __sincosf(ph, &sf, &cf);
      f2 u0; u0.x = c * cf; u0.y = -c * sf;  // U00 = c e^{-i phi}
      f2 u1; u1.x = s * cf; u1.y = s * sf;   // U10 = s e^{+i phi}
      #pragma unroll
      for (int r = 0; r < 64; ++r) {
        if ((r & ~(int)DONE & 63) == 0) {
          f2 a = st[r];
          int r2 = r | (int)TB;
          st[r]  = pk_fma_rot_p(a, u0, pk_mul_bl(a, u0));
          st[r2] = pk_fma_rot_p(a, u1, pk_mul_bl(a, u1));
        }
      }
      l0_reg<Q + 1, DONE | TB>(st, ang, qp);
    } else {
      l0_reg<Q + 1, DONE>(st, ang, qp);
    }
  }
}

// ---- LDS remap: relabel storage (2 stages x 16KB, wave-local, no barriers) ----
// Stage s handles exactly the physical registers {r: bit cb == s} on both sides.
template<int PH>
__device__ __forceinline__ void remap(f2* st, f2* lds, int lane) {
  constexpr int b = PLAN.cb[PH];
  constexpr unsigned LM6 = (1u << b) - 1u;
  constexpr unsigned LM = (1u << (6 + b)) - 1u;
  unsigned B = 0;
  #pragma unroll
  for (int j = 0; j < 6; ++j) B ^= (unsigned)(-(int)((lane >> j) & 1)) & PLAN.phi[PH][j];
  unsigned rBe = (B & LM) | ((B >> 1) & (0x7FFu & ~LM));
  #pragma unroll
  for (int s = 0; s < 2; ++s) {
    #pragma unroll
    for (int r = 0; r < 64; ++r) {
      if (((r >> b) & 1) == s) {
        const int cr = (r & (int)LM6) | ((r >> 1) & (31 & ~(int)LM6));
        lds[(cr << 6) | lane] = st[r];
      }
    }
    asm volatile("s_waitcnt lgkmcnt(0)" ::: "memory");
    #pragma unroll
    for (int rp = 0; rp < 64; ++rp) {
      if (((rp >> b) & 1) == s) {
        st[rp] = lds[rBe ^ PLAN.coffE[PH][rp]];
      }
    }
    asm volatile("s_waitcnt lgkmcnt(0)" ::: "memory");
  }
}

template<int PH, int I>
__device__ __forceinline__ void do_phase(f2* st, const float* ang, const float* __restrict__ qp, int lane, int lane4) {
  if constexpr (I < 6) {
    constexpr int L = 1 + PH / 2;
    constexpr bool REAL = (L == NL - 1);
    constexpr int q = (PH % 2) * 6 + I;
    constexpr unsigned M = PLAN.gm[PH][I];
    constexpr unsigned R = PLAN.gr[PH][I];
    float th0 = qp[(L * NQ + q) * 2 + 0];
    float ph1 = REAL ? 0.f : 0.5f * qp[(L * NQ + q) * 2 + 1];
    gate<M, R, 64, REAL>(st, 0.5f * (ang[q] + th0), ph1, lane, lane4);
    do_phase<PH, I + 1>(st, ang, qp, lane, lane4);
  }
}

__device__ __forceinline__ float redsum(float v, int lane4) {
  v += shx<1>(v, lane4);
  v += shx<2>(v, lane4);
  v += shx<4>(v, lane4);
  v += shx<8>(v, lane4);
  v += shx<16>(v, lane4);
  v += shx<32>(v, lane4);
  return v;
}
__device__ __forceinline__ float fast_tanh(float x) {
  float e = __expf(2.f * x);
  float r = __builtin_amdgcn_rcpf(e + 1.f);
  return 1.f - 2.f * r;
}

template<int Q>
__device__ __forceinline__ void finish(const f2* acc6, float& outv, int lane, int lane4) {
  if constexpr (Q < NQ) {
    constexpr unsigned RLO = PLAN.rf[Q] & 63u;
    float a = (Q & 1) ? acc6[Q / 2].y : acc6[Q / 2].x;
    float sLn = (__popc((int)(RLO & (unsigned)lane)) & 1) ? -a : a;
    float t = redsum(sLn, lane4);
    if (lane == Q) outv = t;
    finish<Q + 1>(acc6, outv, lane, lane4);
  }
}

__global__ __launch_bounds__(64, 2) void qtr_kernel(const float* __restrict__ x,
                                                    const float* __restrict__ W,
                                                    const float* __restrict__ qp,
                                                    float* __restrict__ out) {
  __shared__ f2 ldsb[2048];  // 16KB
  int b = blockIdx.x;
  int lane = threadIdx.x;
  int lane4 = lane << 2;

  // angles[q] = pi * tanh(dot(x[b], W[q]))
  float xv = x[b * FEAT + lane];
  float ang[NQ];
  #pragma unroll
  for (int q = 0; q < NQ; ++q) {
    float prod = redsum(xv * W[q * FEAT + lane], lane4);
    ang[q] = PI_F * fast_tanh(prod);
  }

  // sparse |0..0>
  f2 st[64];
  st[0].x = (lane == 0) ? 1.f : 0.f;
  st[0].y = 0.f;

  l0_lane<0>(st, ang, qp, lane, lane4);
  l0_reg<0, 0u>(st, ang, qp);

  remap<0>(st, ldsb, lane);
  do_phase<0, 0>(st, ang, qp, lane, lane4);
  remap<1>(st, ldsb, lane);
  do_phase<1, 0>(st, ang, qp, lane, lane4);
  remap<2>(st, ldsb, lane);
  do_phase<2, 0>(st, ang, qp, lane, lane4);
  remap<3>(st, ldsb, lane);
  do_phase<3, 0>(st, ang, qp, lane, lane4);

  // probabilities -> 6 packed parity-signed accumulators
  f2 acc6[6];
  #pragma unroll
  for (int j = 0; j < 6; ++j) { acc6[j].x = 0.f; acc6[j].y = 0.f; }
  #pragma unroll
  for (int r = 0; r < 64; ++r) {
    f2 q2 = pk_mul_d(st[r], st[r]);
    float p = q2.x + q2.y;
    f2 pp; pp.x = p; pp.y = p;
    #pragma unroll
    for (int j = 0; j < 6; ++j) {
      const bool n0 = ((__builtin_popcount(((PLAN.rf[2 * j]     >> 6) & 63u) & (unsigned)r)) & 1) != 0;
      const bool n1 = ((__builtin_popcount(((PLAN.rf[2 * j + 1] >> 6) & 63u) & (unsigned)r)) & 1) != 0;
      f2 sg; sg.x = n0 ? -1.f : 1.f; sg.y = n1 ? -1.f : 1.f;
      acc6[j] = pk_fma_d(pp, sg, acc6[j]);
    }
  }

  float outv = 0.f;
  finish<0>(acc6, outv, lane, lane4);

  if (lane < NQ) out[b * NQ + lane] = outv;
}

}  // namespace

extern "C" void kernel_launch(void* const* d_in, const int* in_sizes, int n_in,
                              void* d_out, int out_size, void* d_ws, size_t ws_size,
                              hipStream_t stream) {
  const float* x  = (const float*)d_in[0];
  const float* W  = (const float*)d_in[1];
  const float* qp = (const float*)d_in[2];
  float* out = (float*)d_out;
  qtr_kernel<<<8192, 64, 0, stream>>>(x, W, qp, out);
}

// Round 10
// 131.371 us; speedup vs baseline: 2.4924x; 1.0312x over previous
//
#include <hip/hip_runtime.h>

namespace {

constexpr int NQ = 12;
constexpr int NL = 3;
constexpr int FEAT = 64;
constexpr float PI_F = 3.14159265358979323846f;

typedef float f2 __attribute__((ext_vector_type(2)));

// ============================ constexpr GF(2) toolkit ============================
constexpr int par12(unsigned x) { int p = 0; for (int i = 0; i < 12; ++i) p ^= (int)((x >> i) & 1u); return p; }
constexpr int lead12(unsigned x) { for (int k = 11; k >= 0; --k) if ((x >> k) & 1u) return k; return -1; }

struct Ech { unsigned v[16] = {}; int n = 0; };
constexpr unsigned ech_reduce(const Ech& E, unsigned x) {
  for (int i = 0; i < E.n; ++i) { int lb = lead12(E.v[i]); if (lb >= 0 && ((x >> lb) & 1u)) x ^= E.v[i]; }
  return x;
}
constexpr bool ech_add(Ech& E, unsigned x) {
  unsigned r = ech_reduce(E, x);
  if (!r) return false;
  int lb = lead12(r);
  int pos = E.n;
  for (int i = 0; i < E.n; ++i) { if (lead12(E.v[i]) < lb) { pos = i; break; } }
  for (int i = E.n; i > pos; --i) E.v[i] = E.v[i - 1];
  E.v[pos] = r; E.n++;
  return true;
}

// 4-bit echelon for bank-pair rank tracking
struct Ech4 { unsigned v[4] = {}; int n = 0; };
constexpr int lead4(unsigned x) { for (int k = 3; k >= 0; --k) if ((x >> k) & 1u) return k; return -1; }
constexpr unsigned e4_reduce(const Ech4& E, unsigned x) {
  x &= 15u;
  for (int i = 0; i < E.n; ++i) { int lb = lead4(E.v[i]); if (lb >= 0 && ((x >> lb) & 1u)) x ^= E.v[i]; }
  return x;
}
constexpr bool e4_add(Ech4& E, unsigned x) {
  unsigned r = e4_reduce(E, x);
  if (!r) return false;
  int lb = lead4(r);
  int pos = E.n;
  for (int i = 0; i < E.n; ++i) { if (lead4(E.v[i]) < lb) { pos = i; break; } }
  for (int i = E.n; i > pos; --i) E.v[i] = E.v[i - 1];
  E.v[pos] = r; E.n++;
  return true;
}

constexpr unsigned apmat(const unsigned* rows, unsigned v) {
  unsigned o = 0; for (int k = 0; k < 12; ++k) if (par12(rows[k] & v)) o |= 1u << k; return o;
}
constexpr bool inv12(const unsigned* in, unsigned* out) {
  unsigned a[12] = {}, b[12] = {};
  for (int k = 0; k < 12; ++k) { a[k] = in[k]; b[k] = 1u << k; }
  for (int c = 0; c < 12; ++c) {
    int p = -1;
    for (int r = c; r < 12; ++r) if ((a[r] >> c) & 1u) { p = r; break; }
    if (p < 0) return false;
    unsigned t = a[c]; a[c] = a[p]; a[p] = t; t = b[c]; b[c] = b[p]; b[p] = t;
    for (int r = 0; r < 12; ++r) if (r != c && ((a[r] >> c) & 1u)) { a[r] ^= a[c]; b[r] ^= b[c]; }
  }
  for (int k = 0; k < 12; ++k) out[k] = b[k];
  return true;
}
constexpr unsigned dropb(unsigned x, int t) {  // remove bit t, shift higher bits down (11-bit result)
  unsigned lm = (1u << t) - 1u;
  return (x & lm) | ((x >> 1) & (0x7FFu & ~lm));
}

// ============ logical circuit tracking (deferred CNOT ring, verified r1-r6) ============
struct Logical {
  unsigned m[NL][NQ] = {}, rv[NL][NQ] = {}, rf[NQ] = {};
  bool ok = false;
};
constexpr Logical compute_raw() {
  Logical mp{};
  unsigned col[NQ] = {}, row[NQ] = {};
  for (int b = 0; b < NQ; ++b) { col[b] = 1u << b; row[b] = 1u << b; }
  mp.ok = true;
  for (int L = 0; L < NL; ++L) {
    for (int q = 0; q < NQ; ++q) {
      mp.m[L][q]  = col[NQ - 1 - q];
      mp.rv[L][q] = row[NQ - 1 - q];
      if (par12(mp.m[L][q] & mp.rv[L][q]) != 1) mp.ok = false;
    }
    for (int q = 0; q < NQ; ++q) {
      int bc = NQ - 1 - q;
      int bt = NQ - 1 - ((q + 1) % NQ);
      col[bc] ^= col[bt];
      row[bt] ^= row[bc];
    }
  }
  for (int q = 0; q < NQ; ++q) mp.rf[q] = row[NQ - 1 - q];
  return mp;
}

// ============================ phase/remap plan ============================
// Storage index p: bits [0..5] lane, bits [6..11] reg. 5 epochs: l0 (identity), then 4
// phases (layer1 a/b, layer2 a/b) each with a labeling making all 6 gate masks register-local.
// Epoch transition = 2-stage wave-local LDS permutation (16KB, half the state per stage).
// Chunk invariant: old-half {r: bit cb == s} maps exactly onto new-half {rp: bit cb == s},
// so each stage writes then overwrites the SAME physical register set (no aliasing).
struct Plan {
  unsigned l0m[NQ] = {}, l0r[NQ] = {};
  unsigned gm[4][6] = {};      // storage masks
  unsigned gr[4][6] = {};      // storage parity rows
  unsigned rf[NQ] = {};        // final measurement parity rows
  unsigned phi[4][6] = {};     // old-storage images of new lane basis
  unsigned coffE[4][64] = {};  // per-new-reg old-entry offset (11-bit, chunk bit dropped)
  int cb[4] = {};              // chunk reg-bit (0..5), same coordinate old & new
  bool ok = false;
};

constexpr bool findH(const Ech& G, unsigned rho, unsigned& out) {
  for (unsigned t = 0; t < 12; ++t) {
    unsigned v = 1u << t;
    if (par12(v & rho) == 0 && ech_reduce(G, v)) { out = v; return true; }
  }
  for (unsigned v = 1; v < 4096u; ++v) {
    if (par12(v & rho) == 0 && ech_reduce(G, v)) { out = v; return true; }
  }
  return false;
}

constexpr Plan build_plan() {
  Logical raw = compute_raw();
  Plan P{};
  P.ok = raw.ok;
  for (int q = 0; q < NQ; ++q) { P.l0m[q] = raw.m[0][q]; P.l0r[q] = raw.rv[0][q]; }
  unsigned fwd[12] = {}, invc[12] = {};
  for (int k = 0; k < 12; ++k) { fwd[k] = 1u << k; invc[k] = 1u << k; }
  for (int ph = 0; ph < 4; ++ph) {
    const int L = 1 + ph / 2, q0 = (ph % 2) * 6;
    unsigned ml[6] = {};
    for (int i = 0; i < 6; ++i) ml[i] = raw.m[L][q0 + i];
    bool done = false;
    for (int cbi = 5; cbi >= 0 && !done; --cbi) {
      unsigned rho = fwd[6 + cbi];
      bool bad = false;
      // uc = chunk-carrying reg basis vector (non-orthogonal to rho); prefer a mask
      int idx = -1;
      for (int i = 0; i < 6; ++i) if (par12(ml[i] & rho)) { idx = i; break; }
      unsigned uc = 0;
      Ech W{};  // echelon of rho-perp components of masks
      if (idx >= 0) {
        uc = ml[idx];
        for (int i = 0; i < 6; ++i) {
          if (i == idx) continue;
          unsigned w = par12(ml[i] & rho) ? (ml[i] ^ uc) : ml[i];
          ech_add(W, w);  // dependent -> ignored
        }
        if (W.n > 5) bad = true;
      } else {
        for (int i = 0; i < 6; ++i) ech_add(W, ml[i]);
        if (W.n > 5) bad = true;  // all 6 dims inside the hyperplane: this cb unusable
        if (!bad) {
          bool got = false;
          for (unsigned t = 0; t < 12 && !got; ++t) {
            unsigned v = 1u << t;
            if (par12(v & rho)) { uc = v; got = true; }
          }
          if (!got) bad = true;
        }
      }
      if (bad) continue;
      Ech G{};
      for (int i = 0; i < W.n && !bad; ++i) if (!ech_add(G, W.v[i])) bad = true;
      if (!bad && !ech_add(G, uc)) bad = true;
      if (bad) continue;
      unsigned regH[5] = {};
      int nH = W.n;
      for (int i = 0; i < nH; ++i) regH[i] = W.v[i];
      for (int slot = nH; slot < 5 && !bad; ++slot) {
        unsigned v = 0;
        if (!findH(G, rho, v)) { bad = true; break; }
        regH[slot] = v; ech_add(G, v);
      }
      if (bad) continue;
      // lane basis: prefer old lane columns (identity read base -> clean banks)
      unsigned lam[6] = {};
      for (int j = 0; j < 6 && !bad; ++j) {
        unsigned cand = invc[j];
        if (par12(cand & rho) != 0 || !ech_reduce(G, cand)) {
          if (!findH(G, rho, cand)) { bad = true; break; }
        }
        lam[j] = cand; ech_add(G, cand);
      }
      if (bad) continue;
      // assemble new labeling columns; chunk vector at reg position cbi
      unsigned ncols[12] = {};
      for (int j = 0; j < 6; ++j) ncols[j] = lam[j];
      {
        int w = 0;
        for (int k = 0; k < 6; ++k) ncols[6 + k] = (k == cbi) ? uc : regH[w++];
      }
      unsigned Mrows[12] = {};
      for (int k = 0; k < 12; ++k) {
        unsigned r = 0;
        for (int j = 0; j < 12; ++j) r |= ((ncols[j] >> k) & 1u) << j;
        Mrows[k] = r;
      }
      unsigned fnew[12] = {};
      if (!inv12(Mrows, fnew)) continue;
      // validate
      bool okp = true;
      unsigned gmv[6] = {}, grv[6] = {};
      for (int i = 0; i < 6 && okp; ++i) {
        unsigned SM = apmat(fnew, ml[i]);
        if (SM & 63u) okp = false;
        unsigned sg = 0;
        for (int k = 0; k < 12; ++k) if (par12(raw.rv[L][q0 + i] & ncols[k])) sg |= 1u << k;
        if (par12(SM & sg) != 1) okp = false;
        gmv[i] = SM; grv[i] = sg;
      }
      unsigned phj[6] = {}, Ust[6] = {};
      for (int j = 0; j < 6 && okp; ++j) {
        phj[j] = apmat(fwd, lam[j]);
        if ((phj[j] >> (6 + cbi)) & 1u) okp = false;
      }
      for (int k = 0; k < 6 && okp; ++k) {
        Ust[k] = apmat(fwd, ncols[6 + k]);
        if (((Ust[k] >> (6 + cbi)) & 1u) != (unsigned)(k == cbi ? 1 : 0)) okp = false;
      }
      if (!okp) continue;
      // record
      P.cb[ph] = cbi;
      for (int j = 0; j < 6; ++j) P.phi[ph][j] = phj[j];
      for (int rp = 0; rp < 64; ++rp) {
        unsigned psi = 0;
        for (int i = 0; i < 6; ++i) if ((rp >> i) & 1) psi ^= Ust[i];
        P.coffE[ph][rp] = dropb(psi, 6 + cbi);
      }
      for (int i = 0; i < 6; ++i) { P.gm[ph][i] = gmv[i]; P.gr[ph][i] = grv[i]; }
      for (int k = 0; k < 12; ++k) { fwd[k] = fnew[k]; invc[k] = ncols[k]; }
      done = true;
    }
    if (!done) { P.ok = false; return P; }
  }
  for (int q = 0; q < NQ; ++q) {
    unsigned sg = 0;
    for (int k = 0; k < 12; ++k) if (par12(raw.rf[q] & invc[k])) sg |= 1u << k;
    P.rf[q] = sg;
  }
  return P;
}

constexpr Plan PLAN = build_plan();
static_assert(PLAN.ok, "plan construction failed");

// ============================ packed FP32 primitives (verified r4-r6) ============================
__device__ __forceinline__ f2 pk_mul_bl(f2 a, f2 u) {
  f2 d;
  asm("v_pk_mul_f32 %0, %1, %2 op_sel:[0,0] op_sel_hi:[1,0]" : "=v"(d) : "v"(a), "v"(u));
  return d;
}
__device__ __forceinline__ f2 pk_fma_rot_p(f2 a, f2 u, f2 c) {
  f2 d;
  asm("v_pk_fma_f32 %0, %1, %2, %3 op_sel:[1,1,0] op_sel_hi:[0,1,1] neg_lo:[1,0,0]"
      : "=v"(d) : "v"(a), "v"(u), "v"(c));
  return d;
}
__device__ __forceinline__ f2 pk_fma_rot_m(f2 a, f2 u, f2 c) {
  f2 d;
  asm("v_pk_fma_f32 %0, %1, %2, %3 op_sel:[1,1,0] op_sel_hi:[0,1,1] neg_hi:[1,0,0]"
      : "=v"(d) : "v"(a), "v"(u), "v"(c));
  return d;
}
__device__ __forceinline__ f2 pk_fma_bl_p(f2 p, f2 v, f2 c) {
  f2 d;
  asm("v_pk_fma_f32 %0, %1, %2, %3 op_sel:[0,0,0] op_sel_hi:[1,0,1]"
      : "=v"(d) : "v"(p), "v"(v), "v"(c));
  return d;
}
__device__ __forceinline__ f2 pk_fma_bl_m(f2 p, f2 v, f2 c) {
  f2 d;
  asm("v_pk_fma_f32 %0, %1, %2, %3 op_sel:[0,0,0] op_sel_hi:[1,0,1] neg_lo:[0,1,0] neg_hi:[0,1,0]"
      : "=v"(d) : "v"(p), "v"(v), "v"(c));
  return d;
}
__device__ __forceinline__ f2 pk_mul_d(f2 a, f2 b) {
  f2 d;
  asm("v_pk_mul_f32 %0, %1, %2" : "=v"(d) : "v"(a), "v"(b));
  return d;
}
__device__ __forceinline__ f2 pk_fma_d(f2 a, f2 b, f2 c) {
  f2 d;
  asm("v_pk_fma_f32 %0, %1, %2, %3" : "=v"(d) : "v"(a), "v"(b), "v"(c));
  return d;
}

template<bool REAL>
__device__ __forceinline__ f2 updp(f2 a, f2 p, f2 u, f2 v) {
  if constexpr (REAL) return pk_fma_bl_p(p, v, pk_mul_bl(a, u));
  else return pk_fma_rot_p(p, v, pk_fma_bl_p(p, v, pk_fma_rot_p(a, u, pk_mul_bl(a, u))));
}
template<bool REAL>
__device__ __forceinline__ f2 updm(f2 a, f2 p, f2 u, f2 v) {
  if constexpr (REAL) return pk_fma_bl_m(p, v, pk_mul_bl(a, u));
  else return pk_fma_rot_p(p, v, pk_fma_bl_m(p, v, pk_fma_rot_m(a, u, pk_mul_bl(a, u))));
}

// xor-shuffle (remaining uses: l0 lane gates + reductions)
template<unsigned MLO>
__device__ __forceinline__ float shx(float v, int lane4) {
  if constexpr (MLO == 0u) {
    return v;
  } else if constexpr (MLO < 32u) {
    constexpr int off = (int)((MLO << 10) | 0x1fu);
    return __int_as_float(__builtin_amdgcn_ds_swizzle(__float_as_int(v), off));
  } else {
    int addr = lane4 ^ (int)(MLO << 2);
    return __int_as_float(__builtin_amdgcn_ds_bpermute(addr, __float_as_int(v)));
  }
}

// Fused U = RZ(2*phihalf) * RY(2*ghalf); REAL drops RZ (last layer, phases cancel in |amp|^2).
template<unsigned M, unsigned R, int NREG, bool REAL>
__device__ __forceinline__ void gate(f2* st, float ghalf, float phihalf, int lane, int lane4) {
  float s, c;
  __sincosf(ghalf, &s, &c);
  constexpr unsigned MHI = (M >> 6) & 63u;
  constexpr unsigned MLO = M & 63u;
  constexpr unsigned RHI = (R >> 6) & 63u;
  constexpr unsigned RLO = R & 63u;
  float sL = (__popc((int)(RLO & (unsigned)lane)) & 1) ? -1.f : 1.f;
  f2 u, v;
  if constexpr (REAL) {
    u.x = c;       u.y = 0.f;
    v.x = -s * sL; v.y = 0.f;
  } else {
    float sf, cf;
    __sincosf(phihalf, &sf, &cf);
    u.x = c * cf;         u.y = (-c * sf) * sL;
    v.x = (-s * cf) * sL; v.y = s * sf;
  }
  if constexpr (MLO == 0u) {
    constexpr unsigned TB = MHI & (~MHI + 1u);
    #pragma unroll
    for (int r = 0; r < NREG; ++r) {
      if ((r & (int)TB) == 0) {
        int r2 = r ^ (int)MHI;
        const bool rp = ((__builtin_popcount((unsigned)r & RHI)) & 1) != 0;
        f2 a = st[r], b = st[r2];
        st[r]  = rp ? updm<REAL>(a, b, u, v) : updp<REAL>(a, b, u, v);
        st[r2] = rp ? updp<REAL>(b, a, u, v) : updm<REAL>(b, a, u, v);
      }
    }
  } else {
    #pragma unroll
    for (int r = 0; r < NREG; ++r) {
      f2 p;
      p.x = shx<MLO>(st[r].x, lane4);
      p.y = shx<MLO>(st[r].y, lane4);
      const bool rp = ((__builtin_popcount((unsigned)r & RHI)) & 1) != 0;
      st[r] = rp ? updm<REAL>(st[r], p, u, v) : updp<REAL>(st[r], p, u, v);
    }
  }
}

// ---- layer 0 on sparse |0..0> (identity labeling; all masks single-bit) ----
template<int Q>
__device__ __forceinline__ void l0_lane(f2* st, const float* ang, const float* __restrict__ qp, int lane, int lane4) {
  if constexpr (Q < NQ) {
    constexpr unsigned M = PLAN.l0m[Q];
    if constexpr (M < 64u) {
      gate<M, PLAN.l0r[Q], 1, false>(st, 0.5f * (ang[Q] + qp[Q * 2 + 0]), 0.5f * qp[Q * 2 + 1], lane, lane4);
    }
    l0_lane<Q + 1>(st, ang, qp, lane, lane4);
  }
}
template<int Q, unsigned DONE>
__device__ __forceinline__ void l0_reg(f2* st, const float* ang, const float* __restrict__ qp) {
  if constexpr (Q < NQ) {
    constexpr unsigned M = PLAN.l0m[Q];
    if constexpr (M >= 64u) {
      constexpr unsigned TB = (M >> 6) & 63u;
      float sh = 0.5f * (ang[Q] + qp[Q * 2 + 0]);
      float ph = 0.5f * qp[Q * 2 + 1];
      float s, c, sf, cf;
      __sincosf(sh, &s, &c);
      __sincosf(ph, &sf, &cf);
      f2 u0; u0.x = c * cf; u0.y = -c * sf;  // U00 = c e^{-i phi}
      f2 u1; u1.x = s * cf; u1.y =  s * sf;  // U10 = s e^{+i phi}
      #pragma unroll
      for (int r = 0; r < 64; ++r) {
        if ((r & ~(int)DONE & 63) == 0) {
          f2 a = st[r];
          int r2 = r | (int)TB;
          st[r]  = pk_fma_rot_p(a, u0, pk_mul_bl(a, u0));
          st[r2] = pk_fma_rot_p(a, u1, pk_mul_bl(a, u1));
        }
      }
      l0_reg<Q + 1, DONE | TB>(st, ang, qp);
    } else {
      l0_reg<Q + 1, DONE>(st, ang, qp);
    }
  }
}

// ---- LDS remap: relabel storage (2 stages x 16KB, wave-local, no barriers) ----
// Stage s handles exactly the physical registers {r: bit cb == s} on both sides.
// PAD(a) = a + (a>>5): skewed indexing — injective on [0,2048), applied identically to
// writes and reads (same LDS-slot permutation, correctness invariant). Mixes high
// address bits into the bank index, breaking the XOR rank deficiency that produced
// 17.8M bank conflicts in r6 (the read set rBe^coffE had rank<=2 in bank bits).
__device__ __forceinline__ int pad(int a) { return a + (a >> 5); }

template<int PH>
__device__ __forceinline__ void remap(f2* st, f2* lds, int lane) {
  constexpr int b = PLAN.cb[PH];
  constexpr unsigned LM6 = (1u << b) - 1u;
  constexpr unsigned LM = (1u << (6 + b)) - 1u;
  unsigned B = 0;
  #pragma unroll
  for (int j = 0; j < 6; ++j) B ^= (unsigned)(-(int)((lane >> j) & 1)) & PLAN.phi[PH][j];
  unsigned rBe = (B & LM) | ((B >> 1) & (0x7FFu & ~LM));
  #pragma unroll
  for (int s = 0; s < 2; ++s) {
    #pragma unroll
    for (int r = 0; r < 64; ++r) {
      if (((r >> b) & 1) == s) {
        const int cr = (r & (int)LM6) | ((r >> 1) & (31 & ~(int)LM6));
        lds[pad((cr << 6) | lane)] = st[r];
      }
    }
    asm volatile("s_waitcnt lgkmcnt(0)" ::: "memory");
    #pragma unroll
    for (int rp = 0; rp < 64; ++rp) {
      if (((rp >> b) & 1) == s) {
        st[rp] = lds[pad((int)(rBe ^ PLAN.coffE[PH][rp]))];
      }
    }
    asm volatile("s_waitcnt lgkmcnt(0)" ::: "memory");
  }
}

template<int PH, int I>
__device__ __forceinline__ void do_phase(f2* st, const float* ang, const float* __restrict__ qp, int lane, int lane4) {
  if constexpr (I < 6) {
    constexpr int L = 1 + PH / 2;
    constexpr bool REAL = (L == NL - 1);
    constexpr int q = (PH % 2) * 6 + I;
    constexpr unsigned M = PLAN.gm[PH][I];
    constexpr unsigned R = PLAN.gr[PH][I];
    float th0 = qp[(L * NQ + q) * 2 + 0];
    float ph1 = REAL ? 0.f : 0.5f * qp[(L * NQ + q) * 2 + 1];
    gate<M, R, 64, REAL>(st, 0.5f * (ang[q] + th0), ph1, lane, lane4);
    do_phase<PH, I + 1>(st, ang, qp, lane, lane4);
  }
}

__device__ __forceinline__ float redsum(float v, int lane4) {
  v += shx<1>(v, lane4);
  v += shx<2>(v, lane4);
  v += shx<4>(v, lane4);
  v += shx<8>(v, lane4);
  v += shx<16>(v, lane4);
  v += shx<32>(v, lane4);
  return v;
}
__device__ __forceinline__ float fast_tanh(float x) {
  float e = __expf(2.f * x);
  float r = __builtin_amdgcn_rcpf(e + 1.f);
  return 1.f - 2.f * r;
}

template<int Q>
__device__ __forceinline__ void finish(const f2* acc6, float& outv, int lane, int lane4) {
  if constexpr (Q < NQ) {
    constexpr unsigned RLO = PLAN.rf[Q] & 63u;
    float a = (Q & 1) ? acc6[Q / 2].y : acc6[Q / 2].x;
    float sLn = (__popc((int)(RLO & (unsigned)lane)) & 1) ? -a : a;
    float t = redsum(sLn, lane4);
    if (lane == Q) outv = t;
    finish<Q + 1>(acc6, outv, lane, lane4);
  }
}

__global__ __launch_bounds__(64, 2) void qtr_kernel(const float* __restrict__ x,
                                                    const float* __restrict__ W,
                                                    const float* __restrict__ qp,
                                                    float* __restrict__ out) {
  __shared__ f2 ldsb[2112];  // 16.5KB (2048 + 64 pad slots)
  int b = blockIdx.x;
  int lane = threadIdx.x;
  int lane4 = lane << 2;

  // angles[q] = pi * tanh(dot(x[b], W[q]))
  float xv = x[b * FEAT + lane];
  float ang[NQ];
  #pragma unroll
  for (int q = 0; q < NQ; ++q) {
    float prod = redsum(xv * W[q * FEAT + lane], lane4);
    ang[q] = PI_F * fast_tanh(prod);
  }

  // sparse |0..0>
  f2 st[64];
  st[0].x = (lane == 0) ? 1.f : 0.f;
  st[0].y = 0.f;

  l0_lane<0>(st, ang, qp, lane, lane4);
  l0_reg<0, 0u>(st, ang, qp);

  remap<0>(st, ldsb, lane);
  do_phase<0, 0>(st, ang, qp, lane, lane4);
  remap<1>(st, ldsb, lane);
  do_phase<1, 0>(st, ang, qp, lane, lane4);
  remap<2>(st, ldsb, lane);
  do_phase<2, 0>(st, ang, qp, lane, lane4);
  remap<3>(st, ldsb, lane);
  do_phase<3, 0>(st, ang, qp, lane, lane4);

  // probabilities -> 6 packed parity-signed accumulators
  f2 acc6[6];
  #pragma unroll
  for (int j = 0; j < 6; ++j) { acc6[j].x = 0.f; acc6[j].y = 0.f; }
  #pragma unroll
  for (int r = 0; r < 64; ++r) {
    f2 q2 = pk_mul_d(st[r], st[r]);
    float p = q2.x + q2.y;
    f2 pp; pp.x = p; pp.y = p;
    #pragma unroll
    for (int j = 0; j < 6; ++j) {
      const bool n0 = ((__builtin_popcount(((PLAN.rf[2 * j]     >> 6) & 63u) & (unsigned)r)) & 1) != 0;
      const bool n1 = ((__builtin_popcount(((PLAN.rf[2 * j + 1] >> 6) & 63u) & (unsigned)r)) & 1) != 0;
      f2 sg; sg.x = n0 ? -1.f : 1.f; sg.y = n1 ? -1.f : 1.f;
      acc6[j] = pk_fma_d(pp, sg, acc6[j]);
    }
  }

  float outv = 0.f;
  finish<0>(acc6, outv, lane, lane4);

  if (lane < NQ) out[b * NQ + lane] = outv;
}

}  // namespace

extern "C" void kernel_launch(void* const* d_in, const int* in_sizes, int n_in,
                              void* d_out, int out_size, void* d_ws, size_t ws_size,
                              hipStream_t stream) {
  const float* x  = (const float*)d_in[0];
  const float* W  = (const float*)d_in[1];
  const float* qp = (const float*)d_in[2];
  float* out = (float*)d_out;
  qtr_kernel<<<8192, 64, 0, stream>>>(x, W, qp, out);
}